// Round 8
// baseline (809.307 us; speedup 1.0000x reference)
//
#include <hip/hip_runtime.h>

// ---------------------------------------------------------------------------
// GeneralGNN: 4-layer GCN (skip='all') + MLP head.
// Round 7: 8-way privatized degree histogram (contention-hypothesis test).
// cnt8[c][i]: per-copy counts -> per-copy exclusive offsets (combine) ->
// + rp (folded into scan3) so csr_fill does one random load per edge.
// ---------------------------------------------------------------------------

typedef __bf16 bf16;
typedef __attribute__((ext_vector_type(8))) __bf16 bf16x8;
typedef __attribute__((ext_vector_type(4))) __bf16 bf16x4;
typedef __attribute__((ext_vector_type(4))) float f32x4;

// ---------------- CSR build ----------------
__global__ __launch_bounds__(256) void zero_int(unsigned int* p, int n) {
    int i = blockIdx.x * 256 + threadIdx.x;
    if (i < n) p[i] = 0u;
}

// privatized: copy = blockIdx & 7. rank[e] = old count within (copy,dst).
__global__ __launch_bounds__(256) void hist_dst(const int* __restrict__ ei,
                                                int* cnt8, int* __restrict__ rank,
                                                int n, int E) {
    int e = blockIdx.x * 256 + threadIdx.x;
    if (e < E) {
        int dst = ei[E + e];
        rank[e] = atomicAdd(&cnt8[(blockIdx.x & 7) * n + dst], 1);
    }
}

// per-node: cnt8[c][i] -> exclusive prefix over copies; cnt_tot[i] = total;
// dinv[i] = rsqrt(total+1)
__global__ __launch_bounds__(256) void combine8(int* __restrict__ cnt8,
                                                int* __restrict__ cnt_tot,
                                                float* __restrict__ dinv, int n) {
    int i = blockIdx.x * 256 + threadIdx.x;
    if (i >= n) return;
    int s = 0;
#pragma unroll
    for (int c = 0; c < 8; ++c) {
        int t = cnt8[c * n + i];
        cnt8[c * n + i] = s;
        s += t;
    }
    cnt_tot[i] = s;
    dinv[i] = rsqrtf((float)(s + 1));
}

// level 1: per-block (1024 elems) exclusive scan + block sums.
__global__ __launch_bounds__(256) void scan1(const int* __restrict__ cnt,
                                             int* __restrict__ rp,
                                             int* __restrict__ bsum, int n) {
    __shared__ int sums[256];
    const int t = threadIdx.x;
    const int base = blockIdx.x * 1024 + t * 4;
    int4 v = make_int4(0, 0, 0, 0);
    if (base < n) v = *(const int4*)&cnt[base];          // n % 4 == 0
    int s = v.x + v.y + v.z + v.w;
    sums[t] = s;
    __syncthreads();
#pragma unroll
    for (int off = 1; off < 256; off <<= 1) {
        int u = (t >= off) ? sums[t - off] : 0;
        __syncthreads();
        sums[t] += u;
        __syncthreads();
    }
    int excl = sums[t] - s;
    if (base < n) {
        int4 r;
        r.x = excl;
        r.y = r.x + v.x;
        r.z = r.y + v.y;
        r.w = r.z + v.z;
        *(int4*)&rp[base] = r;
    }
    if (t == 255) bsum[blockIdx.x] = sums[255];
}

// level 2: single block, exclusive scan of nb block sums (nb <= 128)
__global__ __launch_bounds__(128) void scan2(int* __restrict__ bsum, int nb) {
    __shared__ int sums[128];
    const int t = threadIdx.x;
    int s = (t < nb) ? bsum[t] : 0;
    sums[t] = s;
    __syncthreads();
#pragma unroll
    for (int off = 1; off < 128; off <<= 1) {
        int u = (t >= off) ? sums[t - off] : 0;
        __syncthreads();
        sums[t] += u;
        __syncthreads();
    }
    if (t < nb) bsum[t] = sums[t] - s;   // exclusive
}

// level 3: add block offsets to rp; fold final rp into per-copy bases:
// cnt8[c][i] += rp_final[i]. Writes sentinel rp[n] = E.
__global__ __launch_bounds__(256) void scan3(int* __restrict__ rp,
                                             const int* __restrict__ bsum,
                                             int* __restrict__ cnt8, int n, int E) {
    const int base = blockIdx.x * 1024 + threadIdx.x * 4;
    if (base < n) {
        int o = bsum[blockIdx.x];
        int4 r = *(int4*)&rp[base];
        r.x += o; r.y += o; r.z += o; r.w += o;
        *(int4*)&rp[base] = r;
#pragma unroll
        for (int c = 0; c < 8; ++c) {
            int* p = &cnt8[c * n + base];
            p[0] += r.x; p[1] += r.y; p[2] += r.z; p[3] += r.w;
        }
    }
    if (blockIdx.x == 0 && threadIdx.x == 0) rp[n] = E;
}

// csr[cnt8[copy][dst] + rank[e]] = src ; copy = (e>>8)&7 matches hist_dst.
__global__ __launch_bounds__(256) void csr_fill(const int* __restrict__ ei,
                                                const int* __restrict__ cnt8,
                                                const int* __restrict__ rank,
                                                int* __restrict__ csr, int n, int E) {
    const int T = gridDim.x * 256;
    int e = blockIdx.x * 256 + threadIdx.x;
#pragma unroll 4
    for (int i = 0; i < 4; ++i) {
        if (e < E) {
            int dst = ei[E + e];
            csr[cnt8[((e >> 8) & 7) * n + dst] + rank[e]] = ei[e];
        }
        e += T;
    }
}

// ---------------- casts ----------------
__global__ __launch_bounds__(256) void cast_f32_bf16(const float* __restrict__ in,
                                                     bf16* __restrict__ out, long long n4) {
    long long i = (long long)blockIdx.x * 256 + threadIdx.x;
    if (i < n4) {
        float4 v = ((const float4*)in)[i];
        bf16x4 o = {(bf16)v.x, (bf16)v.y, (bf16)v.z, (bf16)v.w};
        ((bf16x4*)out)[i] = o;
    }
}

// all 9 weight transposes in one launch: wt[cum[s] + nn*K + k] = src[s][k*N+nn]
struct TAll {
    const float* src[9];
    int cum[10];
    int N[9];
    int K[9];
};
__global__ __launch_bounds__(256) void transpose_all(TAll d, bf16* __restrict__ wt, int total) {
    int idx = blockIdx.x * 256 + threadIdx.x;
    if (idx >= total) return;
    int seg = 0;
#pragma unroll
    for (int s = 1; s < 9; ++s) if (idx >= d.cum[s]) seg = s;
    int local = idx - d.cum[seg];
    int N = d.N[seg], K = d.K[seg];
    int k = local / N;
    int nn = local - k * N;
    wt[d.cum[seg] + (size_t)nn * K + k] = (bf16)d.src[seg][local];
}

// ---------------- bf16 MFMA GEMM ----------------
// C[M,N] = act( rowscale * ([A1|A2][M,Ktot] @ WT^T) + bias )
// Tile 128x128, BK=64, 4 waves (2x2). global_load_lds width=16 staging:
// linear LDS dest, global source pre-swizzled by chunk ^= (row&7); fragment
// reads apply the same XOR (bank-conflict-free, both-sides pattern).
__global__ __launch_bounds__(256) void gemm_bf16(
    const bf16* __restrict__ A1, int lda1, int K1,
    const bf16* __restrict__ A2, int lda2,
    const bf16* __restrict__ WT,
    const float* __restrict__ bias,
    const float* __restrict__ rowscale,
    void* __restrict__ Cout, int ldc, int M, int Ktot,
    int act, int outf32)
{
    __shared__ bf16 Als[128 * 64];
    __shared__ bf16 Bls[128 * 64];

    const int t = threadIdx.x;
    const int lane = t & 63;
    const int wid = t >> 6;
    const int wm = wid >> 1, wn = wid & 1;
    const int row0 = blockIdx.x * 128;
    const int col0 = blockIdx.y * 128;
    const int nt = Ktot >> 6;

    f32x4 acc[4][4];
#pragma unroll
    for (int mf = 0; mf < 4; ++mf)
#pragma unroll
        for (int nf = 0; nf < 4; ++nf) {
            f32x4 z = {0.f, 0.f, 0.f, 0.f};
            acc[mf][nf] = z;
        }

    int srow[4], scs[4];
#pragma unroll
    for (int i = 0; i < 4; ++i) {
        int ch = wid * 64 + i * 256 + lane;
        int row = ch >> 3, c = ch & 7;
        srow[i] = row;
        scs[i] = (c ^ (row & 7)) * 8;
    }

    for (int kt = 0; kt < nt; ++kt) {
        const int k0 = kt * 64;
        const bf16* Ap; int lda_, kk;
        if (k0 < K1) { Ap = A1; lda_ = lda1; kk = k0; }
        else         { Ap = A2; lda_ = lda2; kk = k0 - K1; }

        __syncthreads();
#pragma unroll
        for (int i = 0; i < 4; ++i) {
            int grow = row0 + srow[i]; if (grow >= M) grow = M - 1;
            const bf16* ga = &Ap[(size_t)grow * lda_ + kk + scs[i]];
            const bf16* gb = &WT[(size_t)(col0 + srow[i]) * Ktot + k0 + scs[i]];
            bf16* la = &Als[(size_t)(wid * 64 + i * 256) * 8];
            bf16* lb = &Bls[(size_t)(wid * 64 + i * 256) * 8];
            __builtin_amdgcn_global_load_lds(
                (const __attribute__((address_space(1))) void*)ga,
                (__attribute__((address_space(3))) void*)la, 16, 0, 0);
            __builtin_amdgcn_global_load_lds(
                (const __attribute__((address_space(1))) void*)gb,
                (__attribute__((address_space(3))) void*)lb, 16, 0, 0);
        }
        asm volatile("s_waitcnt vmcnt(0)" ::: "memory");
        __syncthreads();

#pragma unroll
        for (int ks = 0; ks < 2; ++ks) {
            bf16x8 af[4], bfr[4];
#pragma unroll
            for (int mf = 0; mf < 4; ++mf) {
                int r = wm * 64 + mf * 16 + (lane & 15);
                int ch = (ks * 4 + (lane >> 4)) ^ (r & 7);
                af[mf] = *(const bf16x8*)((const char*)Als + r * 128 + ch * 16);
            }
#pragma unroll
            for (int nf = 0; nf < 4; ++nf) {
                int r = wn * 64 + nf * 16 + (lane & 15);
                int ch = (ks * 4 + (lane >> 4)) ^ (r & 7);
                bfr[nf] = *(const bf16x8*)((const char*)Bls + r * 128 + ch * 16);
            }
#pragma unroll
            for (int mf = 0; mf < 4; ++mf)
#pragma unroll
                for (int nf = 0; nf < 4; ++nf)
                    acc[mf][nf] = __builtin_amdgcn_mfma_f32_16x16x32_bf16(
                        af[mf], bfr[nf], acc[mf][nf], 0, 0, 0);
        }
    }

#pragma unroll
    for (int mf = 0; mf < 4; ++mf) {
        int rbase = row0 + wm * 64 + mf * 16 + (lane >> 4) * 4;
#pragma unroll
        for (int nf = 0; nf < 4; ++nf) {
            int gcol = col0 + wn * 64 + nf * 16 + (lane & 15);
            float bv = bias ? bias[gcol] : 0.f;
#pragma unroll
            for (int i = 0; i < 4; ++i) {
                int grow = rbase + i;
                if (grow >= M) continue;
                float v = acc[mf][nf][i];
                if (rowscale) v *= rowscale[grow];
                v += bv;
                if (act == 1) v = fmaxf(v, 0.f);
                else if (act == 2) v = v > 0.f ? v : 0.1f * v;
                if (outf32) ((float*)Cout)[(size_t)grow * ldc + gcol] = v;
                else        ((bf16*)Cout)[(size_t)grow * ldc + gcol] = (bf16)v;
            }
        }
    }
}

// ---------------- fused gather ----------------
// wave per node; 4 groups x 16 lanes; 4 edges in flight per group (ILP-4).
__global__ __launch_bounds__(256) void gcn_gather(
    const int* __restrict__ rp, const int* __restrict__ csr,
    const bf16* __restrict__ g, const float* __restrict__ dinv,
    const float* __restrict__ b,
    bf16* __restrict__ out, int ldo, int n)
{
    const int node = (int)(((long long)blockIdx.x * 256 + threadIdx.x) >> 6);
    if (node >= n) return;
    const int lane = threadIdx.x & 63;
    const int grp = lane >> 4;
    const int cc = lane & 15;
    const int start = rp[node];
    const int end = rp[node + 1];

    float acc[8];
#pragma unroll
    for (int j = 0; j < 8; ++j) acc[j] = 0.f;

    int j = start + grp;
    for (; j + 12 < end; j += 16) {
        int s0 = csr[j];
        int s1 = csr[j + 4];
        int s2 = csr[j + 8];
        int s3 = csr[j + 12];
        bf16x8 v0 = *(const bf16x8*)&g[(size_t)s0 * 128 + cc * 8];
        bf16x8 v1 = *(const bf16x8*)&g[(size_t)s1 * 128 + cc * 8];
        bf16x8 v2 = *(const bf16x8*)&g[(size_t)s2 * 128 + cc * 8];
        bf16x8 v3 = *(const bf16x8*)&g[(size_t)s3 * 128 + cc * 8];
#pragma unroll
        for (int jj = 0; jj < 8; ++jj)
            acc[jj] += ((float)v0[jj] + (float)v1[jj]) + ((float)v2[jj] + (float)v3[jj]);
    }
    for (; j < end; j += 4) {
        int s0 = csr[j];
        bf16x8 v0 = *(const bf16x8*)&g[(size_t)s0 * 128 + cc * 8];
#pragma unroll
        for (int jj = 0; jj < 8; ++jj) acc[jj] += (float)v0[jj];
    }
#pragma unroll
    for (int jj = 0; jj < 8; ++jj) {
        acc[jj] += __shfl_xor(acc[jj], 16, 64);
        acc[jj] += __shfl_xor(acc[jj], 32, 64);
    }
    if (grp == 0) {
        bf16x8 sv = *(const bf16x8*)&g[(size_t)node * 128 + cc * 8];
        float s = dinv[node];
        bf16x8 o;
#pragma unroll
        for (int jj = 0; jj < 8; ++jj) {
            float v = fmaf(s, acc[jj] + (float)sv[jj], b[cc * 8 + jj]);
            o[jj] = (bf16)fmaxf(v, 0.f);
        }
        *(bf16x8*)&out[(size_t)node * ldo + cc * 8] = o;
    }
}

// ---------------- launcher ----------------
extern "C" void kernel_launch(void* const* d_in, const int* in_sizes, int n_in,
                              void* d_out, int out_size, void* d_ws, size_t ws_size,
                              hipStream_t stream) {
    const float* x      = (const float*)d_in[0];
    const int*   ei     = (const int*)d_in[1];
    const float* pre_w  = (const float*)d_in[2];
    const float* pre_b  = (const float*)d_in[3];
    const float* conv_w[4] = {(const float*)d_in[4], (const float*)d_in[6],
                              (const float*)d_in[8], (const float*)d_in[10]};
    const float* conv_b[4] = {(const float*)d_in[5], (const float*)d_in[7],
                              (const float*)d_in[9], (const float*)d_in[11]};
    const float* post_w1 = (const float*)d_in[12];
    const float* post_b1 = (const float*)d_in[13];
    const float* post_w2 = (const float*)d_in[14];
    const float* post_b2 = (const float*)d_in[15];
    const float* post_w3 = (const float*)d_in[16];
    const float* post_b3 = (const float*)d_in[17];
    const float* post_w4 = (const float*)d_in[18];
    const float* post_b4 = (const float*)d_in[19];

    const int n = in_sizes[0] / 128;    // 100000
    const int E = in_sizes[1] / 2;      // 1600000
    const int nb = (n + 1023) / 1024;   // 98 scan blocks

    // ws layout (bytes)
    size_t off = 0;
    bf16* emb  = (bf16*)((char*)d_ws + off); off += (size_t)n * 512 * 2;
    bf16* g    = (bf16*)((char*)d_ws + off); off += (size_t)n * 128 * 2;
    bf16* h4   = (bf16*)((char*)d_ws + off); off += (size_t)n * 128 * 2;
    bf16* xb   = (bf16*)((char*)d_ws + off); off += (size_t)n * 128 * 2;
    float* dinv = (float*)((char*)d_ws + off); off += (size_t)n * 4;
    int*   rp   = (int*)((char*)d_ws + off); off += (size_t)(n + 4) * 4;
    int*   csr  = (int*)((char*)d_ws + off); off += (size_t)E * 4;
    int*   rank = (int*)((char*)d_ws + off); off += (size_t)E * 4;
    bf16*  wt   = (bf16*)((char*)d_ws + off); off += (size_t)344064 * 2;
    int*   bsum = (int*)((char*)d_ws + off); off += 128 * 4;
    int*   cnt8 = (int*)((char*)d_ws + off); off += (size_t)n * 8 * 4;
    int*   ctot = (int*)((char*)d_ws + off); off += (size_t)n * 4;
    if (ws_size < off) return;  // diagnostic early-out

    bf16* h1 = g;               // post overlays on dead buffers
    bf16* h2 = xb;
    bf16* h3 = emb;

    // weight-pool offsets (elements)
    bf16* pre_wt  = wt;            // [128][128]
    bf16* c_wt0   = wt + 16384;
    bf16* c_wt1   = wt + 32768;
    bf16* c_wt2   = wt + 65536;
    bf16* c_wt3   = wt + 114688;
    bf16* p1_wt   = wt + 180224;   // [128][640]
    bf16* p2_wt   = wt + 262144;
    bf16* p3_wt   = wt + 278528;   // [256][128]
    bf16* p4_wt   = wt + 311296;   // [128][256]
    bf16* c_wt[4] = {c_wt0, c_wt1, c_wt2, c_wt3};

    // ---- CSR build ----
    zero_int<<<(n * 8 + 255) / 256, 256, 0, stream>>>((unsigned int*)cnt8, n * 8);
    hist_dst<<<(E + 255) / 256, 256, 0, stream>>>(ei, cnt8, rank, n, E);
    combine8<<<(n + 255) / 256, 256, 0, stream>>>(cnt8, ctot, dinv, n);
    scan1<<<nb, 256, 0, stream>>>(ctot, rp, bsum, n);
    scan2<<<1, 128, 0, stream>>>(bsum, nb);
    scan3<<<nb, 256, 0, stream>>>(rp, bsum, cnt8, n, E);
    csr_fill<<<(E / 4 + 255) / 256, 256, 0, stream>>>(ei, cnt8, rank, csr, n, E);

    // ---- casts (x) + all weight transposes in one launch ----
    cast_f32_bf16<<<(int)(((long long)n * 32 + 255) / 256), 256, 0, stream>>>(x, xb, (long long)n * 32);
    TAll ta;
    ta.src[0] = pre_w;   ta.K[0] = 128; ta.N[0] = 128;
    ta.src[1] = conv_w[0]; ta.K[1] = 128; ta.N[1] = 128;
    ta.src[2] = conv_w[1]; ta.K[2] = 256; ta.N[2] = 128;
    ta.src[3] = conv_w[2]; ta.K[3] = 384; ta.N[3] = 128;
    ta.src[4] = conv_w[3]; ta.K[4] = 512; ta.N[4] = 128;
    ta.src[5] = post_w1;  ta.K[5] = 640; ta.N[5] = 128;
    ta.src[6] = post_w2;  ta.K[6] = 128; ta.N[6] = 128;
    ta.src[7] = post_w3;  ta.K[7] = 128; ta.N[7] = 256;
    ta.src[8] = post_w4;  ta.K[8] = 256; ta.N[8] = 128;
    ta.cum[0] = 0;
    for (int s = 0; s < 9; ++s) ta.cum[s + 1] = ta.cum[s] + ta.K[s] * ta.N[s];
    const int wtot = ta.cum[9];   // 344064
    transpose_all<<<(wtot + 255) / 256, 256, 0, stream>>>(ta, wt, wtot);

    const int gx = (n + 127) / 128;
    auto gemm = [&](const bf16* A1, int lda1, int K1, const bf16* A2, int lda2,
                    const bf16* WT, const float* bias, const float* rs,
                    void* C, int ldc, int Ktot, int N, int act, int outf32) {
        dim3 grid(gx, N / 128);
        gemm_bf16<<<grid, 256, 0, stream>>>(A1, lda1, K1, A2, lda2, WT, bias, rs,
                                            C, ldc, n, Ktot, act, outf32);
    };

    // pre_mp
    gemm(xb, 128, 128, xb, 128, pre_wt, pre_b, nullptr, emb, 512, 128, 128, 0, 0);

    const int ggrid = (int)(((long long)n * 64 + 255) / 256);
    for (int l = 0; l < 4; ++l) {
        int K = 128 * (l + 1);
        gemm(emb, 512, K, emb, 512, c_wt[l], nullptr, dinv, g, 128, K, 128, 0, 0);
        bf16* out = (l < 3) ? (emb + (size_t)128 * (l + 1)) : h4;
        int ldo = (l < 3) ? 512 : 128;
        gcn_gather<<<ggrid, 256, 0, stream>>>(rp, csr, g, dinv, conv_b[l], out, ldo, n);
    }

    // post_mp
    gemm(emb, 512, 512, h4, 128, p1_wt, post_b1, nullptr, h1, 128, 640, 128, 2, 0);
    gemm(h1, 128, 128, h1, 128, p2_wt, post_b2, nullptr, h2, 128, 128, 128, 1, 0);
    gemm(h2, 128, 128, h2, 128, p3_wt, post_b3, nullptr, h3, 256, 128, 256, 1, 0);
    gemm(h3, 256, 256, h3, 256, p4_wt, post_b4, nullptr, d_out, 128, 256, 128, 0, 1);
}

// Round 9
// 700.475 us; speedup vs baseline: 1.1554x; 1.1554x over previous
//
#include <hip/hip_runtime.h>

// ---------------------------------------------------------------------------
// GeneralGNN: 4-layer GCN (skip='all') + MLP head.
// Round 8: row-local fusion. fused_pre: x->emb->g0 (one kernel, LDS-chained
// MFMA). fused_post: h1->h2->h3->out (h2/h3 never touch HBM). CSR build back
// to simple single-copy (privatization + packing were both null: atomic-rate
// wall). 17 dispatches total.
// ---------------------------------------------------------------------------

typedef __bf16 bf16;
typedef __attribute__((ext_vector_type(8))) __bf16 bf16x8;
typedef __attribute__((ext_vector_type(4))) float f32x4;

// ---------------- CSR build ----------------
__global__ __launch_bounds__(256) void zero_int(int* p, int n) {
    int i = blockIdx.x * 256 + threadIdx.x;
    if (i < n) p[i] = 0;
}

// cnt[dst]++ ; rank[e] = old count (edge's slot within its row)
__global__ __launch_bounds__(256) void hist_dst(const int* __restrict__ ei,
                                                int* cnt, int* __restrict__ rank, int E) {
    int e = blockIdx.x * 256 + threadIdx.x;
    if (e < E) rank[e] = atomicAdd(&cnt[ei[E + e]], 1);
}

// level 1: per-block (1024 elems) exclusive scan + block sums; dinv fused.
// cnt overlays dinv (read-before-write, same thread).
__global__ __launch_bounds__(256) void scan1(const int* __restrict__ cnt,
                                             int* __restrict__ rp,
                                             float* __restrict__ dinv,
                                             int* __restrict__ bsum, int n) {
    __shared__ int sums[256];
    const int t = threadIdx.x;
    const int base = blockIdx.x * 1024 + t * 4;
    int4 v = make_int4(0, 0, 0, 0);
    if (base < n) v = *(const int4*)&cnt[base];          // n % 4 == 0
    int s = v.x + v.y + v.z + v.w;
    sums[t] = s;
    __syncthreads();
#pragma unroll
    for (int off = 1; off < 256; off <<= 1) {
        int u = (t >= off) ? sums[t - off] : 0;
        __syncthreads();
        sums[t] += u;
        __syncthreads();
    }
    int excl = sums[t] - s;
    if (base < n) {
        int4 r;
        r.x = excl;
        r.y = r.x + v.x;
        r.z = r.y + v.y;
        r.w = r.z + v.z;
        *(int4*)&rp[base] = r;
        float4 dv;
        dv.x = rsqrtf((float)(v.x + 1));
        dv.y = rsqrtf((float)(v.y + 1));
        dv.z = rsqrtf((float)(v.z + 1));
        dv.w = rsqrtf((float)(v.w + 1));
        *(float4*)&dinv[base] = dv;
    }
    if (t == 255) bsum[blockIdx.x] = sums[255];
}

__global__ __launch_bounds__(128) void scan2(int* __restrict__ bsum, int nb) {
    __shared__ int sums[128];
    const int t = threadIdx.x;
    int s = (t < nb) ? bsum[t] : 0;
    sums[t] = s;
    __syncthreads();
#pragma unroll
    for (int off = 1; off < 128; off <<= 1) {
        int u = (t >= off) ? sums[t - off] : 0;
        __syncthreads();
        sums[t] += u;
        __syncthreads();
    }
    if (t < nb) bsum[t] = sums[t] - s;   // exclusive
}

__global__ __launch_bounds__(256) void scan3(int* __restrict__ rp,
                                             const int* __restrict__ bsum, int n, int E) {
    const int base = blockIdx.x * 1024 + threadIdx.x * 4;
    if (base < n) {
        int o = bsum[blockIdx.x];
        int4 r = *(int4*)&rp[base];
        r.x += o; r.y += o; r.z += o; r.w += o;
        *(int4*)&rp[base] = r;
    }
    if (blockIdx.x == 0 && threadIdx.x == 0) rp[n] = E;
}

// csr[rp[dst] + rank[e]] = src — no atomics, 4 independent edges per thread
__global__ __launch_bounds__(256) void csr_fill(const int* __restrict__ ei,
                                                const int* __restrict__ rp,
                                                const int* __restrict__ rank,
                                                int* __restrict__ csr, int E) {
    const int T = gridDim.x * 256;
    int e = blockIdx.x * 256 + threadIdx.x;
#pragma unroll 4
    for (int i = 0; i < 4; ++i) {
        if (e < E) csr[rp[ei[E + e]] + rank[e]] = ei[e];
        e += T;
    }
}

// ---------------- weight transposes (one launch) ----------------
struct TAll {
    const float* src[9];
    int cum[10];
    int N[9];
    int K[9];
};
__global__ __launch_bounds__(256) void transpose_all(TAll d, bf16* __restrict__ wt, int total) {
    int idx = blockIdx.x * 256 + threadIdx.x;
    if (idx >= total) return;
    int seg = 0;
#pragma unroll
    for (int s = 1; s < 9; ++s) if (idx >= d.cum[s]) seg = s;
    int local = idx - d.cum[seg];
    int N = d.N[seg], K = d.K[seg];
    int k = local / N;
    int nn = local - k * N;
    wt[d.cum[seg] + (size_t)nn * K + k] = (bf16)d.src[seg][local];
}

// ---------------- shared LDS-layout helpers ----------------
// Staged k-tile layout (per 64-k tile): [row 0..127][chunk 0..7 of 16B],
// content: LDS[row][c] = global[row][c ^ (row&7)]  (both-sides swizzle).
__device__ __forceinline__ void stash_lds(char* H, int r, int c, float v) {
    int kt = c >> 6, w = c & 63;
    int byte = kt * 16384 + r * 128 + (((w >> 3) ^ (r & 7)) * 8 + (w & 7)) * 2;
    *(bf16*)(H + byte) = (bf16)v;
}
__device__ __forceinline__ bf16x8 afrag_lds(const char* H, int kt, int r, int ks, int lane) {
    int ch = (ks * 4 + (lane >> 4)) ^ (r & 7);
    return *(const bf16x8*)(H + kt * 16384 + r * 128 + ch * 16);
}

// ---------------- bf16 MFMA GEMM (conv1..3, post1) ----------------
__global__ __launch_bounds__(256) void gemm_bf16(
    const bf16* __restrict__ A1, int lda1, int K1,
    const bf16* __restrict__ A2, int lda2,
    const bf16* __restrict__ WT,
    const float* __restrict__ bias,
    const float* __restrict__ rowscale,
    void* __restrict__ Cout, int ldc, int M, int Ktot,
    int act, int outf32)
{
    __shared__ bf16 Als[128 * 64];
    __shared__ bf16 Bls[128 * 64];

    const int t = threadIdx.x;
    const int lane = t & 63;
    const int wid = t >> 6;
    const int wm = wid >> 1, wn = wid & 1;
    const int row0 = blockIdx.x * 128;
    const int col0 = blockIdx.y * 128;
    const int nt = Ktot >> 6;

    f32x4 acc[4][4];
#pragma unroll
    for (int mf = 0; mf < 4; ++mf)
#pragma unroll
        for (int nf = 0; nf < 4; ++nf) {
            f32x4 z = {0.f, 0.f, 0.f, 0.f};
            acc[mf][nf] = z;
        }

    int srow[4], scs[4];
#pragma unroll
    for (int i = 0; i < 4; ++i) {
        int ch = wid * 64 + i * 256 + lane;
        int row = ch >> 3, c = ch & 7;
        srow[i] = row;
        scs[i] = (c ^ (row & 7)) * 8;
    }

    for (int kt = 0; kt < nt; ++kt) {
        const int k0 = kt * 64;
        const bf16* Ap; int lda_, kk;
        if (k0 < K1) { Ap = A1; lda_ = lda1; kk = k0; }
        else         { Ap = A2; lda_ = lda2; kk = k0 - K1; }

        __syncthreads();
#pragma unroll
        for (int i = 0; i < 4; ++i) {
            int grow = row0 + srow[i]; if (grow >= M) grow = M - 1;
            const bf16* ga = &Ap[(size_t)grow * lda_ + kk + scs[i]];
            const bf16* gb = &WT[(size_t)(col0 + srow[i]) * Ktot + k0 + scs[i]];
            bf16* la = &Als[(size_t)(wid * 64 + i * 256) * 8];
            bf16* lb = &Bls[(size_t)(wid * 64 + i * 256) * 8];
            __builtin_amdgcn_global_load_lds(
                (const __attribute__((address_space(1))) void*)ga,
                (__attribute__((address_space(3))) void*)la, 16, 0, 0);
            __builtin_amdgcn_global_load_lds(
                (const __attribute__((address_space(1))) void*)gb,
                (__attribute__((address_space(3))) void*)lb, 16, 0, 0);
        }
        asm volatile("s_waitcnt vmcnt(0)" ::: "memory");
        __syncthreads();

#pragma unroll
        for (int ks = 0; ks < 2; ++ks) {
            bf16x8 af[4], bfr[4];
#pragma unroll
            for (int mf = 0; mf < 4; ++mf) {
                int r = wm * 64 + mf * 16 + (lane & 15);
                int ch = (ks * 4 + (lane >> 4)) ^ (r & 7);
                af[mf] = *(const bf16x8*)((const char*)Als + r * 128 + ch * 16);
            }
#pragma unroll
            for (int nf = 0; nf < 4; ++nf) {
                int r = wn * 64 + nf * 16 + (lane & 15);
                int ch = (ks * 4 + (lane >> 4)) ^ (r & 7);
                bfr[nf] = *(const bf16x8*)((const char*)Bls + r * 128 + ch * 16);
            }
#pragma unroll
            for (int mf = 0; mf < 4; ++mf)
#pragma unroll
                for (int nf = 0; nf < 4; ++nf)
                    acc[mf][nf] = __builtin_amdgcn_mfma_f32_16x16x32_bf16(
                        af[mf], bfr[nf], acc[mf][nf], 0, 0, 0);
        }
    }

#pragma unroll
    for (int mf = 0; mf < 4; ++mf) {
        int rbase = row0 + wm * 64 + mf * 16 + (lane >> 4) * 4;
#pragma unroll
        for (int nf = 0; nf < 4; ++nf) {
            int gcol = col0 + wn * 64 + nf * 16 + (lane & 15);
            float bv = bias ? bias[gcol] : 0.f;
#pragma unroll
            for (int i = 0; i < 4; ++i) {
                int grow = rbase + i;
                if (grow >= M) continue;
                float v = acc[mf][nf][i];
                if (rowscale) v *= rowscale[grow];
                v += bv;
                if (act == 1) v = fmaxf(v, 0.f);
                else if (act == 2) v = v > 0.f ? v : 0.1f * v;
                if (outf32) ((float*)Cout)[(size_t)grow * ldc + gcol] = v;
                else        ((bf16*)Cout)[(size_t)grow * ldc + gcol] = (bf16)v;
            }
        }
    }
}

// ---------------- fused_pre: emb = x@W0+b0 ; g = dinv*(emb@Wc0) ----------------
__global__ __launch_bounds__(256) void fused_pre(
    const float* __restrict__ x,       // n x 128 f32
    const bf16* __restrict__ preWT,    // [128][128]
    const float* __restrict__ pre_b,
    const bf16* __restrict__ c0WT,     // [128][128]
    const float* __restrict__ dinv,
    bf16* __restrict__ emb, int lde,
    bf16* __restrict__ g, int M)
{
    __shared__ bf16 Als[128 * 64];
    __shared__ bf16 Bls[128 * 64];
    __shared__ bf16 Hbuf[2][128 * 64];   // emb tile (2 k-tiles), staged layout

    const int t = threadIdx.x;
    const int lane = t & 63;
    const int wid = t >> 6;
    const int wm = wid >> 1, wn = wid & 1;
    const int row0 = blockIdx.x * 128;

    int srow[4], scs[4];
#pragma unroll
    for (int i = 0; i < 4; ++i) {
        int ch = wid * 64 + i * 256 + lane;
        int row = ch >> 3, c = ch & 7;
        srow[i] = row;
        scs[i] = (c ^ (row & 7)) * 8;
    }

    f32x4 acc[4][4];
#pragma unroll
    for (int mf = 0; mf < 4; ++mf)
#pragma unroll
        for (int nf = 0; nf < 4; ++nf) { f32x4 z = {0,0,0,0}; acc[mf][nf] = z; }

    // ---- stage 1: emb = x @ preWT^T + b ----
    for (int kt = 0; kt < 2; ++kt) {
        __syncthreads();
#pragma unroll
        for (int i = 0; i < 4; ++i) {
            int grow = row0 + srow[i]; if (grow >= M) grow = M - 1;
            // A: reg-staged f32->bf16 cast, ds_write to same staged layout
            const float* gx = &x[(size_t)grow * 128 + kt * 64 + scs[i]];
            float4 f0 = *(const float4*)gx;
            float4 f1 = *(const float4*)(gx + 4);
            bf16x8 av = {(bf16)f0.x, (bf16)f0.y, (bf16)f0.z, (bf16)f0.w,
                         (bf16)f1.x, (bf16)f1.y, (bf16)f1.z, (bf16)f1.w};
            *(bf16x8*)((char*)Als + (size_t)(wid * 64 + i * 256 + lane) * 16) = av;
            // B: gload_lds
            const bf16* gb = &preWT[(size_t)srow[i] * 128 + kt * 64 + scs[i]];
            bf16* lb = &Bls[(size_t)(wid * 64 + i * 256) * 8];
            __builtin_amdgcn_global_load_lds(
                (const __attribute__((address_space(1))) void*)gb,
                (__attribute__((address_space(3))) void*)lb, 16, 0, 0);
        }
        asm volatile("s_waitcnt vmcnt(0)" ::: "memory");
        __syncthreads();
#pragma unroll
        for (int ks = 0; ks < 2; ++ks) {
            bf16x8 af[4], bfr[4];
#pragma unroll
            for (int mf = 0; mf < 4; ++mf) {
                int r = wm * 64 + mf * 16 + (lane & 15);
                int ch = (ks * 4 + (lane >> 4)) ^ (r & 7);
                af[mf] = *(const bf16x8*)((const char*)Als + r * 128 + ch * 16);
            }
#pragma unroll
            for (int nf = 0; nf < 4; ++nf) {
                int r = wn * 64 + nf * 16 + (lane & 15);
                int ch = (ks * 4 + (lane >> 4)) ^ (r & 7);
                bfr[nf] = *(const bf16x8*)((const char*)Bls + r * 128 + ch * 16);
            }
#pragma unroll
            for (int mf = 0; mf < 4; ++mf)
#pragma unroll
                for (int nf = 0; nf < 4; ++nf)
                    acc[mf][nf] = __builtin_amdgcn_mfma_f32_16x16x32_bf16(
                        af[mf], bfr[nf], acc[mf][nf], 0, 0, 0);
        }
    }
    __syncthreads();   // all Als/Bls reads done before epilogue reuses nothing; keep order

    // epilogue 1: bias, write emb (global) + Hbuf (LDS)
#pragma unroll
    for (int mf = 0; mf < 4; ++mf) {
        int rl = wm * 64 + mf * 16 + (lane >> 4) * 4;
#pragma unroll
        for (int nf = 0; nf < 4; ++nf) {
            int c = wn * 64 + nf * 16 + (lane & 15);
            float bv = pre_b[c];
#pragma unroll
            for (int i = 0; i < 4; ++i) {
                int r = rl + i;
                float v = acc[mf][nf][i] + bv;
                stash_lds((char*)Hbuf, r, c, v);
                int grow = row0 + r;
                if (grow < M) emb[(size_t)grow * lde + c] = (bf16)v;
            }
        }
    }

    // ---- stage 2: g = dinv * (emb @ c0WT^T) ----
#pragma unroll
    for (int mf = 0; mf < 4; ++mf)
#pragma unroll
        for (int nf = 0; nf < 4; ++nf) { f32x4 z = {0,0,0,0}; acc[mf][nf] = z; }

    for (int kt = 0; kt < 2; ++kt) {
        __syncthreads();
#pragma unroll
        for (int i = 0; i < 4; ++i) {
            const bf16* gb = &c0WT[(size_t)srow[i] * 128 + kt * 64 + scs[i]];
            bf16* lb = &Bls[(size_t)(wid * 64 + i * 256) * 8];
            __builtin_amdgcn_global_load_lds(
                (const __attribute__((address_space(1))) void*)gb,
                (__attribute__((address_space(3))) void*)lb, 16, 0, 0);
        }
        asm volatile("s_waitcnt vmcnt(0)" ::: "memory");
        __syncthreads();
#pragma unroll
        for (int ks = 0; ks < 2; ++ks) {
            bf16x8 af[4], bfr[4];
#pragma unroll
            for (int mf = 0; mf < 4; ++mf) {
                int r = wm * 64 + mf * 16 + (lane & 15);
                af[mf] = afrag_lds((const char*)Hbuf, kt, r, ks, lane);
            }
#pragma unroll
            for (int nf = 0; nf < 4; ++nf) {
                int r = wn * 64 + nf * 16 + (lane & 15);
                int ch = (ks * 4 + (lane >> 4)) ^ (r & 7);
                bfr[nf] = *(const bf16x8*)((const char*)Bls + r * 128 + ch * 16);
            }
#pragma unroll
            for (int mf = 0; mf < 4; ++mf)
#pragma unroll
                for (int nf = 0; nf < 4; ++nf)
                    acc[mf][nf] = __builtin_amdgcn_mfma_f32_16x16x32_bf16(
                        af[mf], bfr[nf], acc[mf][nf], 0, 0, 0);
        }
    }

#pragma unroll
    for (int mf = 0; mf < 4; ++mf) {
        int rbase = row0 + wm * 64 + mf * 16 + (lane >> 4) * 4;
#pragma unroll
        for (int nf = 0; nf < 4; ++nf) {
            int c = wn * 64 + nf * 16 + (lane & 15);
#pragma unroll
            for (int i = 0; i < 4; ++i) {
                int grow = rbase + i;
                if (grow >= M) continue;
                g[(size_t)grow * 128 + c] = (bf16)(acc[mf][nf][i] * dinv[grow]);
            }
        }
    }
}

// ---------------- fused_post: h1 -> h2 -> h3 -> out ----------------
__global__ __launch_bounds__(256) void fused_post(
    const bf16* __restrict__ h1,     // n x 128
    const bf16* __restrict__ W2T,    // [128][128]
    const float* __restrict__ b2,
    const bf16* __restrict__ W3T,    // [256][128]
    const float* __restrict__ b3,
    const bf16* __restrict__ W4T,    // [128][256]
    const float* __restrict__ b4,
    float* __restrict__ out, int M)
{
    __shared__ bf16 Als[128 * 64];
    __shared__ bf16 Bls[128 * 64];
    __shared__ bf16 H2[2][128 * 64];
    __shared__ bf16 H3[2][128 * 64];

    const int t = threadIdx.x;
    const int lane = t & 63;
    const int wid = t >> 6;
    const int wm = wid >> 1, wn = wid & 1;
    const int row0 = blockIdx.x * 128;

    int srow[4], scs[4];
#pragma unroll
    for (int i = 0; i < 4; ++i) {
        int ch = wid * 64 + i * 256 + lane;
        int row = ch >> 3, c = ch & 7;
        srow[i] = row;
        scs[i] = (c ^ (row & 7)) * 8;
    }

    f32x4 acc[4][4], acc3[4][4];
#pragma unroll
    for (int mf = 0; mf < 4; ++mf)
#pragma unroll
        for (int nf = 0; nf < 4; ++nf) {
            f32x4 z = {0,0,0,0};
            acc[mf][nf] = z;
            acc3[mf][nf] = z;
        }

    // ---- stage 1: h2 = relu(h1 @ W2T^T + b2) ----
    for (int kt = 0; kt < 2; ++kt) {
        __syncthreads();
#pragma unroll
        for (int i = 0; i < 4; ++i) {
            int grow = row0 + srow[i]; if (grow >= M) grow = M - 1;
            const bf16* ga = &h1[(size_t)grow * 128 + kt * 64 + scs[i]];
            const bf16* gb = &W2T[(size_t)srow[i] * 128 + kt * 64 + scs[i]];
            bf16* la = &Als[(size_t)(wid * 64 + i * 256) * 8];
            bf16* lb = &Bls[(size_t)(wid * 64 + i * 256) * 8];
            __builtin_amdgcn_global_load_lds(
                (const __attribute__((address_space(1))) void*)ga,
                (__attribute__((address_space(3))) void*)la, 16, 0, 0);
            __builtin_amdgcn_global_load_lds(
                (const __attribute__((address_space(1))) void*)gb,
                (__attribute__((address_space(3))) void*)lb, 16, 0, 0);
        }
        asm volatile("s_waitcnt vmcnt(0)" ::: "memory");
        __syncthreads();
#pragma unroll
        for (int ks = 0; ks < 2; ++ks) {
            bf16x8 af[4], bfr[4];
#pragma unroll
            for (int mf = 0; mf < 4; ++mf) {
                int r = wm * 64 + mf * 16 + (lane & 15);
                int ch = (ks * 4 + (lane >> 4)) ^ (r & 7);
                af[mf] = *(const bf16x8*)((const char*)Als + r * 128 + ch * 16);
            }
#pragma unroll
            for (int nf = 0; nf < 4; ++nf) {
                int r = wn * 64 + nf * 16 + (lane & 15);
                int ch = (ks * 4 + (lane >> 4)) ^ (r & 7);
                bfr[nf] = *(const bf16x8*)((const char*)Bls + r * 128 + ch * 16);
            }
#pragma unroll
            for (int mf = 0; mf < 4; ++mf)
#pragma unroll
                for (int nf = 0; nf < 4; ++nf)
                    acc[mf][nf] = __builtin_amdgcn_mfma_f32_16x16x32_bf16(
                        af[mf], bfr[nf], acc[mf][nf], 0, 0, 0);
        }
    }
    __syncthreads();
    // epilogue 1 -> H2
#pragma unroll
    for (int mf = 0; mf < 4; ++mf) {
        int rl = wm * 64 + mf * 16 + (lane >> 4) * 4;
#pragma unroll
        for (int nf = 0; nf < 4; ++nf) {
            int c = wn * 64 + nf * 16 + (lane & 15);
            float bv = b2[c];
#pragma unroll
            for (int i = 0; i < 4; ++i)
                stash_lds((char*)H2, rl + i, c, fmaxf(acc[mf][nf][i] + bv, 0.f));
        }
    }

    // ---- halves: h3half = relu(h2 @ W3T^T + b3) ; out += h3half @ W4T^T ----
    for (int hh = 0; hh < 2; ++hh) {
        // stage 2
#pragma unroll
        for (int mf = 0; mf < 4; ++mf)
#pragma unroll
            for (int nf = 0; nf < 4; ++nf) { f32x4 z = {0,0,0,0}; acc[mf][nf] = z; }
        for (int kt = 0; kt < 2; ++kt) {
            __syncthreads();
#pragma unroll
            for (int i = 0; i < 4; ++i) {
                const bf16* gb = &W3T[(size_t)(hh * 128 + srow[i]) * 128 + kt * 64 + scs[i]];
                bf16* lb = &Bls[(size_t)(wid * 64 + i * 256) * 8];
                __builtin_amdgcn_global_load_lds(
                    (const __attribute__((address_space(1))) void*)gb,
                    (__attribute__((address_space(3))) void*)lb, 16, 0, 0);
            }
            asm volatile("s_waitcnt vmcnt(0)" ::: "memory");
            __syncthreads();
#pragma unroll
            for (int ks = 0; ks < 2; ++ks) {
                bf16x8 af[4], bfr[4];
#pragma unroll
                for (int mf = 0; mf < 4; ++mf) {
                    int r = wm * 64 + mf * 16 + (lane & 15);
                    af[mf] = afrag_lds((const char*)H2, kt, r, ks, lane);
                }
#pragma unroll
                for (int nf = 0; nf < 4; ++nf) {
                    int r = wn * 64 + nf * 16 + (lane & 15);
                    int ch = (ks * 4 + (lane >> 4)) ^ (r & 7);
                    bfr[nf] = *(const bf16x8*)((const char*)Bls + r * 128 + ch * 16);
                }
#pragma unroll
                for (int mf = 0; mf < 4; ++mf)
#pragma unroll
                    for (int nf = 0; nf < 4; ++nf)
                        acc[mf][nf] = __builtin_amdgcn_mfma_f32_16x16x32_bf16(
                            af[mf], bfr[nf], acc[mf][nf], 0, 0, 0);
            }
        }
        __syncthreads();
        // epilogue 2 -> H3
#pragma unroll
        for (int mf = 0; mf < 4; ++mf) {
            int rl = wm * 64 + mf * 16 + (lane >> 4) * 4;
#pragma unroll
            for (int nf = 0; nf < 4; ++nf) {
                int c = wn * 64 + nf * 16 + (lane & 15);
                float bv = b3[hh * 128 + c];
#pragma unroll
                for (int i = 0; i < 4; ++i)
                    stash_lds((char*)H3, rl + i, c, fmaxf(acc[mf][nf][i] + bv, 0.f));
            }
        }
        // stage 3: out += h3half @ W4T (k-range hh*128..hh*128+127)
        for (int kt = 0; kt < 2; ++kt) {
            __syncthreads();
#pragma unroll
            for (int i = 0; i < 4; ++i) {
                const bf16* gb = &W4T[(size_t)srow[i] * 256 + hh * 128 + kt * 64 + scs[i]];
                bf16* lb = &Bls[(size_t)(wid * 64 + i * 256) * 8];
                __builtin_amdgcn_global_load_lds(
                    (const __attribute__((address_space(1))) void*)gb,
                    (__attribute__((address_space(3))) void*)lb, 16, 0, 0);
            }
            asm volatile("s_waitcnt vmcnt(0)" ::: "memory");
            __syncthreads();
#pragma unroll
            for (int ks = 0; ks < 2; ++ks) {
                bf16x8 af[4], bfr[4];
#pragma unroll
                for (int mf = 0; mf < 4; ++mf) {
                    int r = wm * 64 + mf * 16 + (lane & 15);
                    af[mf] = afrag_lds((const char*)H3, kt, r, ks, lane);
                }
#pragma unroll
                for (int nf = 0; nf < 4; ++nf) {
                    int r = wn * 64 + nf * 16 + (lane & 15);
                    int ch = (ks * 4 + (lane >> 4)) ^ (r & 7);
                    bfr[nf] = *(const bf16x8*)((const char*)Bls + r * 128 + ch * 16);
                }
#pragma unroll
                for (int mf = 0; mf < 4; ++mf)
#pragma unroll
                    for (int nf = 0; nf < 4; ++nf)
                        acc3[mf][nf] = __builtin_amdgcn_mfma_f32_16x16x32_bf16(
                            af[mf], bfr[nf], acc3[mf][nf], 0, 0, 0);
            }
        }
        __syncthreads();
    }

    // final epilogue: out = acc3 + b4 (f32)
#pragma unroll
    for (int mf = 0; mf < 4; ++mf) {
        int rbase = row0 + wm * 64 + mf * 16 + (lane >> 4) * 4;
#pragma unroll
        for (int nf = 0; nf < 4; ++nf) {
            int c = wn * 64 + nf * 16 + (lane & 15);
            float bv = b4[c];
#pragma unroll
            for (int i = 0; i < 4; ++i) {
                int grow = rbase + i;
                if (grow < M) out[(size_t)grow * 128 + c] = acc3[mf][nf][i] + bv;
            }
        }
    }
}

// ---------------- fused gather ----------------
__global__ __launch_bounds__(256) void gcn_gather(
    const int* __restrict__ rp, const int* __restrict__ csr,
    const bf16* __restrict__ g, const float* __restrict__ dinv,
    const float* __restrict__ b,
    bf16* __restrict__ out, int ldo, int n)
{
    const int node = (int)(((long long)blockIdx.x * 256 + threadIdx.x) >> 6);
    if (node >= n) return;
    const int lane = threadIdx.x & 63;
    const int grp = lane >> 4;
    const int cc = lane & 15;
    const int start = rp[node];
    const int end = rp[node + 1];

    float acc[8];
#pragma unroll
    for (int j = 0; j < 8; ++j) acc[j] = 0.f;

    int j = start + grp;
    for (; j + 12 < end; j += 16) {
        int s0 = csr[j];
        int s1 = csr[j + 4];
        int s2 = csr[j + 8];
        int s3 = csr[j + 12];
        bf16x8 v0 = *(const bf16x8*)&g[(size_t)s0 * 128 + cc * 8];
        bf16x8 v1 = *(const bf16x8*)&g[(size_t)s1 * 128 + cc * 8];
        bf16x8 v2 = *(const bf16x8*)&g[(size_t)s2 * 128 + cc * 8];
        bf16x8 v3 = *(const bf16x8*)&g[(size_t)s3 * 128 + cc * 8];
#pragma unroll
        for (int jj = 0; jj < 8; ++jj)
            acc[jj] += ((float)v0[jj] + (float)v1[jj]) + ((float)v2[jj] + (float)v3[jj]);
    }
    for (; j < end; j += 4) {
        int s0 = csr[j];
        bf16x8 v0 = *(const bf16x8*)&g[(size_t)s0 * 128 + cc * 8];
#pragma unroll
        for (int jj = 0; jj < 8; ++jj) acc[jj] += (float)v0[jj];
    }
#pragma unroll
    for (int jj = 0; jj < 8; ++jj) {
        acc[jj] += __shfl_xor(acc[jj], 16, 64);
        acc[jj] += __shfl_xor(acc[jj], 32, 64);
    }
    if (grp == 0) {
        bf16x8 sv = *(const bf16x8*)&g[(size_t)node * 128 + cc * 8];
        float s = dinv[node];
        bf16x8 o;
#pragma unroll
        for (int jj = 0; jj < 8; ++jj) {
            float v = fmaf(s, acc[jj] + (float)sv[jj], b[cc * 8 + jj]);
            o[jj] = (bf16)fmaxf(v, 0.f);
        }
        *(bf16x8*)&out[(size_t)node * ldo + cc * 8] = o;
    }
}

// ---------------- launcher ----------------
extern "C" void kernel_launch(void* const* d_in, const int* in_sizes, int n_in,
                              void* d_out, int out_size, void* d_ws, size_t ws_size,
                              hipStream_t stream) {
    const float* x      = (const float*)d_in[0];
    const int*   ei     = (const int*)d_in[1];
    const float* pre_w  = (const float*)d_in[2];
    const float* pre_b  = (const float*)d_in[3];
    const float* conv_w[4] = {(const float*)d_in[4], (const float*)d_in[6],
                              (const float*)d_in[8], (const float*)d_in[10]};
    const float* conv_b[4] = {(const float*)d_in[5], (const float*)d_in[7],
                              (const float*)d_in[9], (const float*)d_in[11]};
    const float* post_w1 = (const float*)d_in[12];
    const float* post_b1 = (const float*)d_in[13];
    const float* post_w2 = (const float*)d_in[14];
    const float* post_b2 = (const float*)d_in[15];
    const float* post_w3 = (const float*)d_in[16];
    const float* post_b3 = (const float*)d_in[17];
    const float* post_w4 = (const float*)d_in[18];
    const float* post_b4 = (const float*)d_in[19];

    const int n = in_sizes[0] / 128;    // 100000
    const int E = in_sizes[1] / 2;      // 1600000
    const int nb = (n + 1023) / 1024;   // 98 scan blocks

    // ws layout (bytes)
    size_t off = 0;
    bf16* emb  = (bf16*)((char*)d_ws + off); off += (size_t)n * 512 * 2;
    bf16* g    = (bf16*)((char*)d_ws + off); off += (size_t)n * 128 * 2;
    bf16* h4   = (bf16*)((char*)d_ws + off); off += (size_t)n * 128 * 2;
    float* dinv = (float*)((char*)d_ws + off); off += (size_t)n * 4;
    int*   rp   = (int*)((char*)d_ws + off); off += (size_t)(n + 4) * 4;
    int*   csr  = (int*)((char*)d_ws + off); off += (size_t)E * 4;
    int*   rank = (int*)((char*)d_ws + off); off += (size_t)E * 4;
    bf16*  wt   = (bf16*)((char*)d_ws + off); off += (size_t)344064 * 2;
    int*   bsum = (int*)((char*)d_ws + off); off += 128 * 4;
    if (ws_size < off) return;  // diagnostic early-out

    int* cnt = (int*)dinv;      // overlay during CSR build
    bf16* h1 = g;               // post1 output overlays g (dead after gather3)

    // weight-pool offsets (elements)
    bf16* pre_wt  = wt;            // [128][128]
    bf16* c_wt0   = wt + 16384;
    bf16* c_wt1   = wt + 32768;
    bf16* c_wt2   = wt + 65536;
    bf16* c_wt3   = wt + 114688;
    bf16* p1_wt   = wt + 180224;   // [128][640]
    bf16* p2_wt   = wt + 262144;
    bf16* p3_wt   = wt + 278528;   // [256][128]
    bf16* p4_wt   = wt + 311296;   // [128][256]
    bf16* c_wt[4] = {c_wt0, c_wt1, c_wt2, c_wt3};

    // ---- CSR build ----
    zero_int<<<(n + 255) / 256, 256, 0, stream>>>(cnt, n);
    hist_dst<<<(E + 255) / 256, 256, 0, stream>>>(ei, cnt, rank, E);
    scan1<<<nb, 256, 0, stream>>>(cnt, rp, dinv, bsum, n);
    scan2<<<1, 128, 0, stream>>>(bsum, nb);
    scan3<<<nb, 256, 0, stream>>>(rp, bsum, n, E);
    csr_fill<<<(E / 4 + 255) / 256, 256, 0, stream>>>(ei, rp, rank, csr, E);

    // ---- all weight transposes in one launch ----
    TAll ta;
    ta.src[0] = pre_w;   ta.K[0] = 128; ta.N[0] = 128;
    ta.src[1] = conv_w[0]; ta.K[1] = 128; ta.N[1] = 128;
    ta.src[2] = conv_w[1]; ta.K[2] = 256; ta.N[2] = 128;
    ta.src[3] = conv_w[2]; ta.K[3] = 384; ta.N[3] = 128;
    ta.src[4] = conv_w[3]; ta.K[4] = 512; ta.N[4] = 128;
    ta.src[5] = post_w1;  ta.K[5] = 640; ta.N[5] = 128;
    ta.src[6] = post_w2;  ta.K[6] = 128; ta.N[6] = 128;
    ta.src[7] = post_w3;  ta.K[7] = 128; ta.N[7] = 256;
    ta.src[8] = post_w4;  ta.K[8] = 256; ta.N[8] = 128;
    ta.cum[0] = 0;
    for (int s = 0; s < 9; ++s) ta.cum[s + 1] = ta.cum[s] + ta.K[s] * ta.N[s];
    const int wtot = ta.cum[9];   // 344064
    transpose_all<<<(wtot + 255) / 256, 256, 0, stream>>>(ta, wt, wtot);

    const int gx = (n + 127) / 128;   // 782
    auto gemm = [&](const bf16* A1, int lda1, int K1, const bf16* A2, int lda2,
                    const bf16* WT, const float* bias, const float* rs,
                    void* C, int ldc, int Ktot, int N, int act, int outf32) {
        dim3 grid(gx, N / 128);
        gemm_bf16<<<grid, 256, 0, stream>>>(A1, lda1, K1, A2, lda2, WT, bias, rs,
                                            C, ldc, n, Ktot, act, outf32);
    };

    const int ggrid = (int)(((long long)n * 64 + 255) / 256);
    for (int l = 0; l < 4; ++l) {
        if (l == 0) {
            fused_pre<<<gx, 256, 0, stream>>>(x, pre_wt, pre_b, c_wt0, dinv,
                                              emb, 512, g, n);
        } else {
            int K = 128 * (l + 1);
            gemm(emb, 512, K, emb, 512, c_wt[l], nullptr, dinv, g, 128, K, 128, 0, 0);
        }
        bf16* out = (l < 3) ? (emb + (size_t)128 * (l + 1)) : h4;
        int ldo = (l < 3) ? 512 : 128;
        gcn_gather<<<ggrid, 256, 0, stream>>>(rp, csr, g, dinv, conv_b[l], out, ldo, n);
    }

    // post_mp
    gemm(emb, 512, 512, h4, 128, p1_wt, post_b1, nullptr, h1, 128, 640, 128, 2, 0);
    fused_post<<<gx, 256, 0, stream>>>(h1, p2_wt, post_b2, p3_wt, post_b3,
                                       p4_wt, post_b4, (float*)d_out, n);
}

// Round 10
// 676.944 us; speedup vs baseline: 1.1955x; 1.0348x over previous
//
#include <hip/hip_runtime.h>

// ---------------------------------------------------------------------------
// GeneralGNN: 4-layer GCN (skip='all') + MLP head.
// Round 9: occupancy fix for fused kernels.
//  fused_post: 64-row tile + LDS union (H3 overlays A-staging) = 48KB -> 3
//  blocks/CU (was 96KB -> 1 block/CU, 8% occupancy, all pipes idle).
//  fused_pre: Als overlays Hbuf[0:16K] = 48KB -> 3 blocks/CU.
// ---------------------------------------------------------------------------

typedef __bf16 bf16;
typedef __attribute__((ext_vector_type(8))) __bf16 bf16x8;
typedef __attribute__((ext_vector_type(4))) float f32x4;

// ---------------- CSR build ----------------
__global__ __launch_bounds__(256) void zero_int(int* p, int n) {
    int i = blockIdx.x * 256 + threadIdx.x;
    if (i < n) p[i] = 0;
}

__global__ __launch_bounds__(256) void hist_dst(const int* __restrict__ ei,
                                                int* cnt, int* __restrict__ rank, int E) {
    int e = blockIdx.x * 256 + threadIdx.x;
    if (e < E) rank[e] = atomicAdd(&cnt[ei[E + e]], 1);
}

__global__ __launch_bounds__(256) void scan1(const int* __restrict__ cnt,
                                             int* __restrict__ rp,
                                             float* __restrict__ dinv,
                                             int* __restrict__ bsum, int n) {
    __shared__ int sums[256];
    const int t = threadIdx.x;
    const int base = blockIdx.x * 1024 + t * 4;
    int4 v = make_int4(0, 0, 0, 0);
    if (base < n) v = *(const int4*)&cnt[base];
    int s = v.x + v.y + v.z + v.w;
    sums[t] = s;
    __syncthreads();
#pragma unroll
    for (int off = 1; off < 256; off <<= 1) {
        int u = (t >= off) ? sums[t - off] : 0;
        __syncthreads();
        sums[t] += u;
        __syncthreads();
    }
    int excl = sums[t] - s;
    if (base < n) {
        int4 r;
        r.x = excl;
        r.y = r.x + v.x;
        r.z = r.y + v.y;
        r.w = r.z + v.z;
        *(int4*)&rp[base] = r;
        float4 dv;
        dv.x = rsqrtf((float)(v.x + 1));
        dv.y = rsqrtf((float)(v.y + 1));
        dv.z = rsqrtf((float)(v.z + 1));
        dv.w = rsqrtf((float)(v.w + 1));
        *(float4*)&dinv[base] = dv;
    }
    if (t == 255) bsum[blockIdx.x] = sums[255];
}

__global__ __launch_bounds__(128) void scan2(int* __restrict__ bsum, int nb) {
    __shared__ int sums[128];
    const int t = threadIdx.x;
    int s = (t < nb) ? bsum[t] : 0;
    sums[t] = s;
    __syncthreads();
#pragma unroll
    for (int off = 1; off < 128; off <<= 1) {
        int u = (t >= off) ? sums[t - off] : 0;
        __syncthreads();
        sums[t] += u;
        __syncthreads();
    }
    if (t < nb) bsum[t] = sums[t] - s;
}

__global__ __launch_bounds__(256) void scan3(int* __restrict__ rp,
                                             const int* __restrict__ bsum, int n, int E) {
    const int base = blockIdx.x * 1024 + threadIdx.x * 4;
    if (base < n) {
        int o = bsum[blockIdx.x];
        int4 r = *(int4*)&rp[base];
        r.x += o; r.y += o; r.z += o; r.w += o;
        *(int4*)&rp[base] = r;
    }
    if (blockIdx.x == 0 && threadIdx.x == 0) rp[n] = E;
}

__global__ __launch_bounds__(256) void csr_fill(const int* __restrict__ ei,
                                                const int* __restrict__ rp,
                                                const int* __restrict__ rank,
                                                int* __restrict__ csr, int E) {
    const int T = gridDim.x * 256;
    int e = blockIdx.x * 256 + threadIdx.x;
#pragma unroll 4
    for (int i = 0; i < 4; ++i) {
        if (e < E) csr[rp[ei[E + e]] + rank[e]] = ei[e];
        e += T;
    }
}

// ---------------- weight transposes (one launch) ----------------
struct TAll {
    const float* src[9];
    int cum[10];
    int N[9];
    int K[9];
};
__global__ __launch_bounds__(256) void transpose_all(TAll d, bf16* __restrict__ wt, int total) {
    int idx = blockIdx.x * 256 + threadIdx.x;
    if (idx >= total) return;
    int seg = 0;
#pragma unroll
    for (int s = 1; s < 9; ++s) if (idx >= d.cum[s]) seg = s;
    int local = idx - d.cum[seg];
    int N = d.N[seg], K = d.K[seg];
    int k = local / N;
    int nn = local - k * N;
    wt[d.cum[seg] + (size_t)nn * K + k] = (bf16)d.src[seg][local];
}

// ---------------- LDS-layout helpers ----------------
// staged layout: per k-tile [rows][8 chunks of 16B], LDS[r][c] = glob[r][c^(r&7)]
// ktStride = rows*128 bytes.
__device__ __forceinline__ void stash_lds(char* H, int ktStride, int r, int c, float v) {
    int kt = c >> 6, w = c & 63;
    int byte = kt * ktStride + r * 128 + (((w >> 3) ^ (r & 7)) * 8 + (w & 7)) * 2;
    *(bf16*)(H + byte) = (bf16)v;
}
__device__ __forceinline__ bf16x8 afrag_lds(const char* H, int ktStride, int kt, int r, int ks, int lane) {
    int ch = (ks * 4 + (lane >> 4)) ^ (r & 7);
    return *(const bf16x8*)(H + kt * ktStride + r * 128 + ch * 16);
}

// ---------------- bf16 MFMA GEMM (conv1..3, post1) ----------------
__global__ __launch_bounds__(256) void gemm_bf16(
    const bf16* __restrict__ A1, int lda1, int K1,
    const bf16* __restrict__ A2, int lda2,
    const bf16* __restrict__ WT,
    const float* __restrict__ bias,
    const float* __restrict__ rowscale,
    void* __restrict__ Cout, int ldc, int M, int Ktot,
    int act, int outf32)
{
    __shared__ bf16 Als[128 * 64];
    __shared__ bf16 Bls[128 * 64];

    const int t = threadIdx.x;
    const int lane = t & 63;
    const int wid = t >> 6;
    const int wm = wid >> 1, wn = wid & 1;
    const int row0 = blockIdx.x * 128;
    const int col0 = blockIdx.y * 128;
    const int nt = Ktot >> 6;

    f32x4 acc[4][4];
#pragma unroll
    for (int mf = 0; mf < 4; ++mf)
#pragma unroll
        for (int nf = 0; nf < 4; ++nf) {
            f32x4 z = {0.f, 0.f, 0.f, 0.f};
            acc[mf][nf] = z;
        }

    int srow[4], scs[4];
#pragma unroll
    for (int i = 0; i < 4; ++i) {
        int ch = wid * 64 + i * 256 + lane;
        int row = ch >> 3, c = ch & 7;
        srow[i] = row;
        scs[i] = (c ^ (row & 7)) * 8;
    }

    for (int kt = 0; kt < nt; ++kt) {
        const int k0 = kt * 64;
        const bf16* Ap; int lda_, kk;
        if (k0 < K1) { Ap = A1; lda_ = lda1; kk = k0; }
        else         { Ap = A2; lda_ = lda2; kk = k0 - K1; }

        __syncthreads();
#pragma unroll
        for (int i = 0; i < 4; ++i) {
            int grow = row0 + srow[i]; if (grow >= M) grow = M - 1;
            const bf16* ga = &Ap[(size_t)grow * lda_ + kk + scs[i]];
            const bf16* gb = &WT[(size_t)(col0 + srow[i]) * Ktot + k0 + scs[i]];
            bf16* la = &Als[(size_t)(wid * 64 + i * 256) * 8];
            bf16* lb = &Bls[(size_t)(wid * 64 + i * 256) * 8];
            __builtin_amdgcn_global_load_lds(
                (const __attribute__((address_space(1))) void*)ga,
                (__attribute__((address_space(3))) void*)la, 16, 0, 0);
            __builtin_amdgcn_global_load_lds(
                (const __attribute__((address_space(1))) void*)gb,
                (__attribute__((address_space(3))) void*)lb, 16, 0, 0);
        }
        asm volatile("s_waitcnt vmcnt(0)" ::: "memory");
        __syncthreads();

#pragma unroll
        for (int ks = 0; ks < 2; ++ks) {
            bf16x8 af[4], bfr[4];
#pragma unroll
            for (int mf = 0; mf < 4; ++mf) {
                int r = wm * 64 + mf * 16 + (lane & 15);
                int ch = (ks * 4 + (lane >> 4)) ^ (r & 7);
                af[mf] = *(const bf16x8*)((const char*)Als + r * 128 + ch * 16);
            }
#pragma unroll
            for (int nf = 0; nf < 4; ++nf) {
                int r = wn * 64 + nf * 16 + (lane & 15);
                int ch = (ks * 4 + (lane >> 4)) ^ (r & 7);
                bfr[nf] = *(const bf16x8*)((const char*)Bls + r * 128 + ch * 16);
            }
#pragma unroll
            for (int mf = 0; mf < 4; ++mf)
#pragma unroll
                for (int nf = 0; nf < 4; ++nf)
                    acc[mf][nf] = __builtin_amdgcn_mfma_f32_16x16x32_bf16(
                        af[mf], bfr[nf], acc[mf][nf], 0, 0, 0);
        }
    }

#pragma unroll
    for (int mf = 0; mf < 4; ++mf) {
        int rbase = row0 + wm * 64 + mf * 16 + (lane >> 4) * 4;
#pragma unroll
        for (int nf = 0; nf < 4; ++nf) {
            int gcol = col0 + wn * 64 + nf * 16 + (lane & 15);
            float bv = bias ? bias[gcol] : 0.f;
#pragma unroll
            for (int i = 0; i < 4; ++i) {
                int grow = rbase + i;
                if (grow >= M) continue;
                float v = acc[mf][nf][i];
                if (rowscale) v *= rowscale[grow];
                v += bv;
                if (act == 1) v = fmaxf(v, 0.f);
                else if (act == 2) v = v > 0.f ? v : 0.1f * v;
                if (outf32) ((float*)Cout)[(size_t)grow * ldc + gcol] = v;
                else        ((bf16*)Cout)[(size_t)grow * ldc + gcol] = (bf16)v;
            }
        }
    }
}

// ---------------- fused_pre: emb = x@W0+b0 ; g = dinv*(emb@Wc0) ----------------
// LDS union 48KB: [Hbuf 32K][Bls 16K]; Als = Hbuf[0:16K] (dead before Hbuf write)
__global__ __launch_bounds__(256) void fused_pre(
    const float* __restrict__ x,
    const bf16* __restrict__ preWT,
    const float* __restrict__ pre_b,
    const bf16* __restrict__ c0WT,
    const float* __restrict__ dinv,
    bf16* __restrict__ emb, int lde,
    bf16* __restrict__ g, int M)
{
    __shared__ char lds[49152];
    bf16* Hbuf = (bf16*)lds;             // 2kt x 128r x 128B
    bf16* Bls  = (bf16*)(lds + 32768);
    bf16* Als  = Hbuf;                   // stage-1 A staging (16KB)

    const int t = threadIdx.x;
    const int lane = t & 63;
    const int wid = t >> 6;
    const int wm = wid >> 1, wn = wid & 1;
    const int row0 = blockIdx.x * 128;

    int srow[4], scs[4];
#pragma unroll
    for (int i = 0; i < 4; ++i) {
        int ch = wid * 64 + i * 256 + lane;
        int row = ch >> 3, c = ch & 7;
        srow[i] = row;
        scs[i] = (c ^ (row & 7)) * 8;
    }

    f32x4 acc[4][4];
#pragma unroll
    for (int mf = 0; mf < 4; ++mf)
#pragma unroll
        for (int nf = 0; nf < 4; ++nf) { f32x4 z = {0,0,0,0}; acc[mf][nf] = z; }

    // ---- stage 1: emb = x @ preWT^T + b ----
    for (int kt = 0; kt < 2; ++kt) {
        __syncthreads();
#pragma unroll
        for (int i = 0; i < 4; ++i) {
            int grow = row0 + srow[i]; if (grow >= M) grow = M - 1;
            const float* gx = &x[(size_t)grow * 128 + kt * 64 + scs[i]];
            float4 f0 = *(const float4*)gx;
            float4 f1 = *(const float4*)(gx + 4);
            bf16x8 av = {(bf16)f0.x, (bf16)f0.y, (bf16)f0.z, (bf16)f0.w,
                         (bf16)f1.x, (bf16)f1.y, (bf16)f1.z, (bf16)f1.w};
            *(bf16x8*)((char*)Als + (size_t)(wid * 64 + i * 256 + lane) * 16) = av;
            const bf16* gb = &preWT[(size_t)srow[i] * 128 + kt * 64 + scs[i]];
            bf16* lb = &Bls[(size_t)(wid * 64 + i * 256) * 8];
            __builtin_amdgcn_global_load_lds(
                (const __attribute__((address_space(1))) void*)gb,
                (__attribute__((address_space(3))) void*)lb, 16, 0, 0);
        }
        asm volatile("s_waitcnt vmcnt(0)" ::: "memory");
        __syncthreads();
#pragma unroll
        for (int ks = 0; ks < 2; ++ks) {
            bf16x8 af[4], bfr[4];
#pragma unroll
            for (int mf = 0; mf < 4; ++mf) {
                int r = wm * 64 + mf * 16 + (lane & 15);
                int ch = (ks * 4 + (lane >> 4)) ^ (r & 7);
                af[mf] = *(const bf16x8*)((const char*)Als + r * 128 + ch * 16);
            }
#pragma unroll
            for (int nf = 0; nf < 4; ++nf) {
                int r = wn * 64 + nf * 16 + (lane & 15);
                int ch = (ks * 4 + (lane >> 4)) ^ (r & 7);
                bfr[nf] = *(const bf16x8*)((const char*)Bls + r * 128 + ch * 16);
            }
#pragma unroll
            for (int mf = 0; mf < 4; ++mf)
#pragma unroll
                for (int nf = 0; nf < 4; ++nf)
                    acc[mf][nf] = __builtin_amdgcn_mfma_f32_16x16x32_bf16(
                        af[mf], bfr[nf], acc[mf][nf], 0, 0, 0);
        }
    }
    __syncthreads();   // all Als reads done before Hbuf overwrite

    // epilogue 1: bias; write emb (global) + Hbuf (LDS)
#pragma unroll
    for (int mf = 0; mf < 4; ++mf) {
        int rl = wm * 64 + mf * 16 + (lane >> 4) * 4;
#pragma unroll
        for (int nf = 0; nf < 4; ++nf) {
            int c = wn * 64 + nf * 16 + (lane & 15);
            float bv = pre_b[c];
#pragma unroll
            for (int i = 0; i < 4; ++i) {
                int r = rl + i;
                float v = acc[mf][nf][i] + bv;
                stash_lds((char*)Hbuf, 16384, r, c, v);
                int grow = row0 + r;
                if (grow < M) emb[(size_t)grow * lde + c] = (bf16)v;
            }
        }
    }

    // ---- stage 2: g = dinv * (emb @ c0WT^T) ----
#pragma unroll
    for (int mf = 0; mf < 4; ++mf)
#pragma unroll
        for (int nf = 0; nf < 4; ++nf) { f32x4 z = {0,0,0,0}; acc[mf][nf] = z; }

    for (int kt = 0; kt < 2; ++kt) {
        __syncthreads();
#pragma unroll
        for (int i = 0; i < 4; ++i) {
            const bf16* gb = &c0WT[(size_t)srow[i] * 128 + kt * 64 + scs[i]];
            bf16* lb = &Bls[(size_t)(wid * 64 + i * 256) * 8];
            __builtin_amdgcn_global_load_lds(
                (const __attribute__((address_space(1))) void*)gb,
                (__attribute__((address_space(3))) void*)lb, 16, 0, 0);
        }
        asm volatile("s_waitcnt vmcnt(0)" ::: "memory");
        __syncthreads();
#pragma unroll
        for (int ks = 0; ks < 2; ++ks) {
            bf16x8 af[4], bfr[4];
#pragma unroll
            for (int mf = 0; mf < 4; ++mf) {
                int r = wm * 64 + mf * 16 + (lane & 15);
                af[mf] = afrag_lds((const char*)Hbuf, 16384, kt, r, ks, lane);
            }
#pragma unroll
            for (int nf = 0; nf < 4; ++nf) {
                int r = wn * 64 + nf * 16 + (lane & 15);
                int ch = (ks * 4 + (lane >> 4)) ^ (r & 7);
                bfr[nf] = *(const bf16x8*)((const char*)Bls + r * 128 + ch * 16);
            }
#pragma unroll
            for (int mf = 0; mf < 4; ++mf)
#pragma unroll
                for (int nf = 0; nf < 4; ++nf)
                    acc[mf][nf] = __builtin_amdgcn_mfma_f32_16x16x32_bf16(
                        af[mf], bfr[nf], acc[mf][nf], 0, 0, 0);
        }
    }

#pragma unroll
    for (int mf = 0; mf < 4; ++mf) {
        int rbase = row0 + wm * 64 + mf * 16 + (lane >> 4) * 4;
#pragma unroll
        for (int nf = 0; nf < 4; ++nf) {
            int c = wn * 64 + nf * 16 + (lane & 15);
#pragma unroll
            for (int i = 0; i < 4; ++i) {
                int grow = rbase + i;
                if (grow >= M) continue;
                g[(size_t)grow * 128 + c] = (bf16)(acc[mf][nf][i] * dinv[grow]);
            }
        }
    }
}

// ---------------- fused_post: h1 -> h2 -> h3 -> out (64-row tile) ----------------
// LDS union 48KB: [H2 16K][Bls 16K][H3 16K]; Als = H3[0:8K] (stage-1 only).
// Per-wave output 32x64: acc[2][4].
__global__ __launch_bounds__(256) void fused_post(
    const bf16* __restrict__ h1,     // n x 128
    const bf16* __restrict__ W2T,    // [128][128]
    const float* __restrict__ b2,
    const bf16* __restrict__ W3T,    // [256][128]
    const float* __restrict__ b3,
    const bf16* __restrict__ W4T,    // [128][256]
    const float* __restrict__ b4,
    float* __restrict__ out, int M)
{
    __shared__ char lds[49152];
    bf16* H2  = (bf16*)lds;              // 2kt x 64r x 128B
    bf16* Bls = (bf16*)(lds + 16384);    // 128r x 64k
    bf16* H3  = (bf16*)(lds + 32768);    // 2kt x 64r x 128B
    bf16* Als = H3;                      // stage-1 h1 staging (8KB)

    const int t = threadIdx.x;
    const int lane = t & 63;
    const int wid = t >> 6;
    const int wm = wid >> 1, wn = wid & 1;
    const int row0 = blockIdx.x * 64;

    int srow[4], scs[4];
#pragma unroll
    for (int i = 0; i < 4; ++i) {
        int ch = wid * 64 + i * 256 + lane;
        int row = ch >> 3, c = ch & 7;
        srow[i] = row;
        scs[i] = (c ^ (row & 7)) * 8;
    }

    f32x4 acc[2][4], acc3[2][4];
#pragma unroll
    for (int mf = 0; mf < 2; ++mf)
#pragma unroll
        for (int nf = 0; nf < 4; ++nf) {
            f32x4 z = {0,0,0,0};
            acc[mf][nf] = z;
            acc3[mf][nf] = z;
        }

    // ---- stage 1: h2 = relu(h1 @ W2T^T + b2) ----
    for (int kt = 0; kt < 2; ++kt) {
        __syncthreads();
        // A: 64x64 tile = 512 chunks, 2 per thread
#pragma unroll
        for (int i = 0; i < 2; ++i) {
            int grow = row0 + srow[i]; if (grow >= M) grow = M - 1;
            const bf16* ga = &h1[(size_t)grow * 128 + kt * 64 + scs[i]];
            bf16* la = &Als[(size_t)(wid * 64 + i * 256) * 8];
            __builtin_amdgcn_global_load_lds(
                (const __attribute__((address_space(1))) void*)ga,
                (__attribute__((address_space(3))) void*)la, 16, 0, 0);
        }
        // B: 128x64 tile = 1024 chunks, 4 per thread
#pragma unroll
        for (int i = 0; i < 4; ++i) {
            const bf16* gb = &W2T[(size_t)srow[i] * 128 + kt * 64 + scs[i]];
            bf16* lb = &Bls[(size_t)(wid * 64 + i * 256) * 8];
            __builtin_amdgcn_global_load_lds(
                (const __attribute__((address_space(1))) void*)gb,
                (__attribute__((address_space(3))) void*)lb, 16, 0, 0);
        }
        asm volatile("s_waitcnt vmcnt(0)" ::: "memory");
        __syncthreads();
#pragma unroll
        for (int ks = 0; ks < 2; ++ks) {
            bf16x8 af[2], bfr[4];
#pragma unroll
            for (int mf = 0; mf < 2; ++mf) {
                int r = wm * 32 + mf * 16 + (lane & 15);
                int ch = (ks * 4 + (lane >> 4)) ^ (r & 7);
                af[mf] = *(const bf16x8*)((const char*)Als + r * 128 + ch * 16);
            }
#pragma unroll
            for (int nf = 0; nf < 4; ++nf) {
                int r = wn * 64 + nf * 16 + (lane & 15);
                int ch = (ks * 4 + (lane >> 4)) ^ (r & 7);
                bfr[nf] = *(const bf16x8*)((const char*)Bls + r * 128 + ch * 16);
            }
#pragma unroll
            for (int mf = 0; mf < 2; ++mf)
#pragma unroll
                for (int nf = 0; nf < 4; ++nf)
                    acc[mf][nf] = __builtin_amdgcn_mfma_f32_16x16x32_bf16(
                        af[mf], bfr[nf], acc[mf][nf], 0, 0, 0);
        }
    }
    __syncthreads();   // Als (=H3[0:8K]) reads done; H2 writes begin
    // epilogue 1 -> H2
#pragma unroll
    for (int mf = 0; mf < 2; ++mf) {
        int rl = wm * 32 + mf * 16 + (lane >> 4) * 4;
#pragma unroll
        for (int nf = 0; nf < 4; ++nf) {
            int c = wn * 64 + nf * 16 + (lane & 15);
            float bv = b2[c];
#pragma unroll
            for (int i = 0; i < 4; ++i)
                stash_lds((char*)H2, 8192, rl + i, c, fmaxf(acc[mf][nf][i] + bv, 0.f));
        }
    }

    // ---- halves: h3half = relu(h2 @ W3T^T + b3) ; out += h3half @ W4T^T ----
    for (int hh = 0; hh < 2; ++hh) {
#pragma unroll
        for (int mf = 0; mf < 2; ++mf)
#pragma unroll
            for (int nf = 0; nf < 4; ++nf) { f32x4 z = {0,0,0,0}; acc[mf][nf] = z; }
        // stage 2: acc = H2 @ W3T(half hh)
        for (int kt = 0; kt < 2; ++kt) {
            __syncthreads();
#pragma unroll
            for (int i = 0; i < 4; ++i) {
                const bf16* gb = &W3T[(size_t)(hh * 128 + srow[i]) * 128 + kt * 64 + scs[i]];
                bf16* lb = &Bls[(size_t)(wid * 64 + i * 256) * 8];
                __builtin_amdgcn_global_load_lds(
                    (const __attribute__((address_space(1))) void*)gb,
                    (__attribute__((address_space(3))) void*)lb, 16, 0, 0);
            }
            asm volatile("s_waitcnt vmcnt(0)" ::: "memory");
            __syncthreads();
#pragma unroll
            for (int ks = 0; ks < 2; ++ks) {
                bf16x8 af[2], bfr[4];
#pragma unroll
                for (int mf = 0; mf < 2; ++mf) {
                    int r = wm * 32 + mf * 16 + (lane & 15);
                    af[mf] = afrag_lds((const char*)H2, 8192, kt, r, ks, lane);
                }
#pragma unroll
                for (int nf = 0; nf < 4; ++nf) {
                    int r = wn * 64 + nf * 16 + (lane & 15);
                    int ch = (ks * 4 + (lane >> 4)) ^ (r & 7);
                    bfr[nf] = *(const bf16x8*)((const char*)Bls + r * 128 + ch * 16);
                }
#pragma unroll
                for (int mf = 0; mf < 2; ++mf)
#pragma unroll
                    for (int nf = 0; nf < 4; ++nf)
                        acc[mf][nf] = __builtin_amdgcn_mfma_f32_16x16x32_bf16(
                            af[mf], bfr[nf], acc[mf][nf], 0, 0, 0);
            }
        }
        __syncthreads();   // H3 reads (prev hh stage 3) + Bls reads done
        // epilogue 2 -> H3
#pragma unroll
        for (int mf = 0; mf < 2; ++mf) {
            int rl = wm * 32 + mf * 16 + (lane >> 4) * 4;
#pragma unroll
            for (int nf = 0; nf < 4; ++nf) {
                int c = wn * 64 + nf * 16 + (lane & 15);
                float bv = b3[hh * 128 + c];
#pragma unroll
                for (int i = 0; i < 4; ++i)
                    stash_lds((char*)H3, 8192, rl + i, c, fmaxf(acc[mf][nf][i] + bv, 0.f));
            }
        }
        // stage 3: acc3 += H3 @ W4T (k range hh*128 .. +127)
        for (int kt = 0; kt < 2; ++kt) {
            __syncthreads();
#pragma unroll
            for (int i = 0; i < 4; ++i) {
                const bf16* gb = &W4T[(size_t)srow[i] * 256 + hh * 128 + kt * 64 + scs[i]];
                bf16* lb = &Bls[(size_t)(wid * 64 + i * 256) * 8];
                __builtin_amdgcn_global_load_lds(
                    (const __attribute__((address_space(1))) void*)gb,
                    (__attribute__((address_space(3))) void*)lb, 16, 0, 0);
            }
            asm volatile("s_waitcnt vmcnt(0)" ::: "memory");
            __syncthreads();
#pragma unroll
            for (int ks = 0; ks < 2; ++ks) {
                bf16x8 af[2], bfr[4];
#pragma unroll
                for (int mf = 0; mf < 2; ++mf) {
                    int r = wm * 32 + mf * 16 + (lane & 15);
                    af[mf] = afrag_lds((const char*)H3, 8192, kt, r, ks, lane);
                }
#pragma unroll
                for (int nf = 0; nf < 4; ++nf) {
                    int r = wn * 64 + nf * 16 + (lane & 15);
                    int ch = (ks * 4 + (lane >> 4)) ^ (r & 7);
                    bfr[nf] = *(const bf16x8*)((const char*)Bls + r * 128 + ch * 16);
                }
#pragma unroll
                for (int mf = 0; mf < 2; ++mf)
#pragma unroll
                    for (int nf = 0; nf < 4; ++nf)
                        acc3[mf][nf] = __builtin_amdgcn_mfma_f32_16x16x32_bf16(
                            af[mf], bfr[nf], acc3[mf][nf], 0, 0, 0);
            }
        }
    }

    // final epilogue: out = acc3 + b4 (f32)
#pragma unroll
    for (int mf = 0; mf < 2; ++mf) {
        int rbase = row0 + wm * 32 + mf * 16 + (lane >> 4) * 4;
#pragma unroll
        for (int nf = 0; nf < 4; ++nf) {
            int c = wn * 64 + nf * 16 + (lane & 15);
            float bv = b4[c];
#pragma unroll
            for (int i = 0; i < 4; ++i) {
                int grow = rbase + i;
                if (grow < M) out[(size_t)grow * 128 + c] = acc3[mf][nf][i] + bv;
            }
        }
    }
}

// ---------------- fused gather ----------------
__global__ __launch_bounds__(256) void gcn_gather(
    const int* __restrict__ rp, const int* __restrict__ csr,
    const bf16* __restrict__ g, const float* __restrict__ dinv,
    const float* __restrict__ b,
    bf16* __restrict__ out, int ldo, int n)
{
    const int node = (int)(((long long)blockIdx.x * 256 + threadIdx.x) >> 6);
    if (node >= n) return;
    const int lane = threadIdx.x & 63;
    const int grp = lane >> 4;
    const int cc = lane & 15;
    const int start = rp[node];
    const int end = rp[node + 1];

    float acc[8];
#pragma unroll
    for (int j = 0; j < 8; ++j) acc[j] = 0.f;

    int j = start + grp;
    for (; j + 12 < end; j += 16) {
        int s0 = csr[j];
        int s1 = csr[j + 4];
        int s2 = csr[j + 8];
        int s3 = csr[j + 12];
        bf16x8 v0 = *(const bf16x8*)&g[(size_t)s0 * 128 + cc * 8];
        bf16x8 v1 = *(const bf16x8*)&g[(size_t)s1 * 128 + cc * 8];
        bf16x8 v2 = *(const bf16x8*)&g[(size_t)s2 * 128 + cc * 8];
        bf16x8 v3 = *(const bf16x8*)&g[(size_t)s3 * 128 + cc * 8];
#pragma unroll
        for (int jj = 0; jj < 8; ++jj)
            acc[jj] += ((float)v0[jj] + (float)v1[jj]) + ((float)v2[jj] + (float)v3[jj]);
    }
    for (; j < end; j += 4) {
        int s0 = csr[j];
        bf16x8 v0 = *(const bf16x8*)&g[(size_t)s0 * 128 + cc * 8];
#pragma unroll
        for (int jj = 0; jj < 8; ++jj) acc[jj] += (float)v0[jj];
    }
#pragma unroll
    for (int jj = 0; jj < 8; ++jj) {
        acc[jj] += __shfl_xor(acc[jj], 16, 64);
        acc[jj] += __shfl_xor(acc[jj], 32, 64);
    }
    if (grp == 0) {
        bf16x8 sv = *(const bf16x8*)&g[(size_t)node * 128 + cc * 8];
        float s = dinv[node];
        bf16x8 o;
#pragma unroll
        for (int jj = 0; jj < 8; ++jj) {
            float v = fmaf(s, acc[jj] + (float)sv[jj], b[cc * 8 + jj]);
            o[jj] = (bf16)fmaxf(v, 0.f);
        }
        *(bf16x8*)&out[(size_t)node * ldo + cc * 8] = o;
    }
}

// ---------------- launcher ----------------
extern "C" void kernel_launch(void* const* d_in, const int* in_sizes, int n_in,
                              void* d_out, int out_size, void* d_ws, size_t ws_size,
                              hipStream_t stream) {
    const float* x      = (const float*)d_in[0];
    const int*   ei     = (const int*)d_in[1];
    const float* pre_w  = (const float*)d_in[2];
    const float* pre_b  = (const float*)d_in[3];
    const float* conv_w[4] = {(const float*)d_in[4], (const float*)d_in[6],
                              (const float*)d_in[8], (const float*)d_in[10]};
    const float* conv_b[4] = {(const float*)d_in[5], (const float*)d_in[7],
                              (const float*)d_in[9], (const float*)d_in[11]};
    const float* post_w1 = (const float*)d_in[12];
    const float* post_b1 = (const float*)d_in[13];
    const float* post_w2 = (const float*)d_in[14];
    const float* post_b2 = (const float*)d_in[15];
    const float* post_w3 = (const float*)d_in[16];
    const float* post_b3 = (const float*)d_in[17];
    const float* post_w4 = (const float*)d_in[18];
    const float* post_b4 = (const float*)d_in[19];

    const int n = in_sizes[0] / 128;    // 100000
    const int E = in_sizes[1] / 2;      // 1600000
    const int nb = (n + 1023) / 1024;   // 98 scan blocks

    // ws layout (bytes)
    size_t off = 0;
    bf16* emb  = (bf16*)((char*)d_ws + off); off += (size_t)n * 512 * 2;
    bf16* g    = (bf16*)((char*)d_ws + off); off += (size_t)n * 128 * 2;
    bf16* h4   = (bf16*)((char*)d_ws + off); off += (size_t)n * 128 * 2;
    float* dinv = (float*)((char*)d_ws + off); off += (size_t)n * 4;
    int*   rp   = (int*)((char*)d_ws + off); off += (size_t)(n + 4) * 4;
    int*   csr  = (int*)((char*)d_ws + off); off += (size_t)E * 4;
    int*   rank = (int*)((char*)d_ws + off); off += (size_t)E * 4;
    bf16*  wt   = (bf16*)((char*)d_ws + off); off += (size_t)344064 * 2;
    int*   bsum = (int*)((char*)d_ws + off); off += 128 * 4;
    if (ws_size < off) return;  // diagnostic early-out

    int* cnt = (int*)dinv;      // overlay during CSR build
    bf16* h1 = g;               // post1 output overlays g (dead after gather3)

    // weight-pool offsets (elements)
    bf16* pre_wt  = wt;            // [128][128]
    bf16* c_wt0   = wt + 16384;
    bf16* c_wt1   = wt + 32768;
    bf16* c_wt2   = wt + 65536;
    bf16* c_wt3   = wt + 114688;
    bf16* p1_wt   = wt + 180224;   // [128][640]
    bf16* p2_wt   = wt + 262144;
    bf16* p3_wt   = wt + 278528;   // [256][128]
    bf16* p4_wt   = wt + 311296;   // [128][256]
    bf16* c_wt[4] = {c_wt0, c_wt1, c_wt2, c_wt3};

    // ---- CSR build ----
    zero_int<<<(n + 255) / 256, 256, 0, stream>>>(cnt, n);
    hist_dst<<<(E + 255) / 256, 256, 0, stream>>>(ei, cnt, rank, E);
    scan1<<<nb, 256, 0, stream>>>(cnt, rp, dinv, bsum, n);
    scan2<<<1, 128, 0, stream>>>(bsum, nb);
    scan3<<<nb, 256, 0, stream>>>(rp, bsum, n, E);
    csr_fill<<<(E / 4 + 255) / 256, 256, 0, stream>>>(ei, rp, rank, csr, E);

    // ---- all weight transposes in one launch ----
    TAll ta;
    ta.src[0] = pre_w;   ta.K[0] = 128; ta.N[0] = 128;
    ta.src[1] = conv_w[0]; ta.K[1] = 128; ta.N[1] = 128;
    ta.src[2] = conv_w[1]; ta.K[2] = 256; ta.N[2] = 128;
    ta.src[3] = conv_w[2]; ta.K[3] = 384; ta.N[3] = 128;
    ta.src[4] = conv_w[3]; ta.K[4] = 512; ta.N[4] = 128;
    ta.src[5] = post_w1;  ta.K[5] = 640; ta.N[5] = 128;
    ta.src[6] = post_w2;  ta.K[6] = 128; ta.N[6] = 128;
    ta.src[7] = post_w3;  ta.K[7] = 128; ta.N[7] = 256;
    ta.src[8] = post_w4;  ta.K[8] = 256; ta.N[8] = 128;
    ta.cum[0] = 0;
    for (int s = 0; s < 9; ++s) ta.cum[s + 1] = ta.cum[s] + ta.K[s] * ta.N[s];
    const int wtot = ta.cum[9];   // 344064
    transpose_all<<<(wtot + 255) / 256, 256, 0, stream>>>(ta, wt, wtot);

    const int gx = (n + 127) / 128;   // 782
    const int gx2 = (n + 63) / 64;    // 1563
    auto gemm = [&](const bf16* A1, int lda1, int K1, const bf16* A2, int lda2,
                    const bf16* WT, const float* bias, const float* rs,
                    void* C, int ldc, int Ktot, int N, int act, int outf32) {
        dim3 grid(gx, N / 128);
        gemm_bf16<<<grid, 256, 0, stream>>>(A1, lda1, K1, A2, lda2, WT, bias, rs,
                                            C, ldc, n, Ktot, act, outf32);
    };

    const int ggrid = (int)(((long long)n * 64 + 255) / 256);
    for (int l = 0; l < 4; ++l) {
        if (l == 0) {
            fused_pre<<<gx, 256, 0, stream>>>(x, pre_wt, pre_b, c_wt0, dinv,
                                              emb, 512, g, n);
        } else {
            int K = 128 * (l + 1);
            gemm(emb, 512, K, emb, 512, c_wt[l], nullptr, dinv, g, 128, K, 128, 0, 0);
        }
        bf16* out = (l < 3) ? (emb + (size_t)128 * (l + 1)) : h4;
        int ldo = (l < 3) ? 512 : 128;
        gcn_gather<<<ggrid, 256, 0, stream>>>(rp, csr, g, dinv, conv_b[l], out, ldo, n);
    }

    // post_mp
    gemm(emb, 512, 512, h4, 128, p1_wt, post_b1, nullptr, h1, 128, 640, 128, 2, 0);
    fused_post<<<gx2, 256, 0, stream>>>(h1, p2_wt, post_b2, p3_wt, post_b3,
                                        p4_wt, post_b4, (float*)d_out, n);
}

// Round 11
// 607.737 us; speedup vs baseline: 1.3317x; 1.1139x over previous
//
#include <hip/hip_runtime.h>

// ---------------------------------------------------------------------------
// GeneralGNN: 4-layer GCN (skip='all') + MLP head.
// Round 10: atomic-free CSR build via bucket partition (radix-style).
//   A: per-block LDS bucket histogram (196 buckets = dst>>9)
//   B: per-bucket exclusive scan across blocks;  B2: bucket bases
//   C: scatter edges (src,dst) to bucket-sorted order (LDS cursors only)
//   D: per-bucket LDS histogram+scan -> rp, dinv, csr (L2-local fill)
// Replaces hist_dst(70us, returning-atomic wall) + scans + csr_fill(~50us
// line-RMW churn). GEMM/gather/fused kernels unchanged from round 9.
// ---------------------------------------------------------------------------

typedef __bf16 bf16;
typedef __attribute__((ext_vector_type(8))) __bf16 bf16x8;
typedef __attribute__((ext_vector_type(4))) float f32x4;

#define BSHIFT 9                 // bucket = dst >> 9  (512 nodes/bucket)
#define PCHUNK 4096              // edges per partition block

// ---- Pass A: per-(bucket, block) counts; no global atomics ----
__global__ __launch_bounds__(256) void part_count(const int* __restrict__ ei,
                                                  int* __restrict__ bcountT,
                                                  int NBKT, int NBLK, int E) {
    __shared__ int cnt[256];
    const int t = threadIdx.x, blk = blockIdx.x;
    if (t < NBKT) cnt[t] = 0;
    __syncthreads();
    const int base = blk * PCHUNK;
#pragma unroll
    for (int i = 0; i < 16; ++i) {
        int e = base + i * 256 + t;
        if (e < E) atomicAdd(&cnt[ei[E + e] >> BSHIFT], 1);   // LDS atomic
    }
    __syncthreads();
    if (t < NBKT) bcountT[t * NBLK + blk] = cnt[t];
}

// ---- Pass B: per-bucket exclusive scan of its row (across blocks) ----
__global__ __launch_bounds__(256) void part_scanb(int* __restrict__ bcountT,
                                                  int* __restrict__ btot, int NBLK) {
    __shared__ int sums[256];
    const int b = blockIdx.x, t = threadIdx.x;
    int* row = &bcountT[(size_t)b * NBLK];
    const int chunk = (NBLK + 255) / 256;
    const int lo = t * chunk, hi = min(lo + chunk, NBLK);
    int s = 0;
    for (int i = lo; i < hi; ++i) s += row[i];
    sums[t] = s;
    __syncthreads();
#pragma unroll
    for (int off = 1; off < 256; off <<= 1) {
        int u = (t >= off) ? sums[t - off] : 0;
        __syncthreads();
        sums[t] += u;
        __syncthreads();
    }
    int run = sums[t] - s;
    for (int i = lo; i < hi; ++i) { int c = row[i]; row[i] = run; run += c; }
    if (t == 255) btot[b] = sums[255];
}

// ---- Pass B2: bucket bases (exclusive scan of btot); bbase[NBKT] = E ----
__global__ __launch_bounds__(256) void part_scant(const int* __restrict__ btot,
                                                  int* __restrict__ bbase, int NBKT, int E) {
    __shared__ int sums[256];
    const int t = threadIdx.x;
    int s = (t < NBKT) ? btot[t] : 0;
    sums[t] = s;
    __syncthreads();
#pragma unroll
    for (int off = 1; off < 256; off <<= 1) {
        int u = (t >= off) ? sums[t - off] : 0;
        __syncthreads();
        sums[t] += u;
        __syncthreads();
    }
    if (t < NBKT) bbase[t] = sums[t] - s;
    if (t == 0) bbase[NBKT] = E;
}

// ---- Pass C: scatter edges to bucket-sorted order ----
__global__ __launch_bounds__(256) void part_scatter(const int* __restrict__ ei,
                                                    const int* __restrict__ bcountT,
                                                    const int* __restrict__ bbase,
                                                    int2* __restrict__ sorted,
                                                    int NBKT, int NBLK, int E) {
    __shared__ int cur[256];
    const int t = threadIdx.x, blk = blockIdx.x;
    if (t < NBKT) cur[t] = bbase[t] + bcountT[(size_t)t * NBLK + blk];
    __syncthreads();
    const int base = blk * PCHUNK;
#pragma unroll
    for (int i = 0; i < 16; ++i) {
        int e = base + i * 256 + t;
        if (e < E) {
            int src = ei[e], dst = ei[E + e];
            int pos = atomicAdd(&cur[dst >> BSHIFT], 1);      // LDS atomic
            sorted[pos] = make_int2(src, dst);
        }
    }
}

// ---- Pass D: per-bucket CSR rows + rp + dinv (all traffic L2-local) ----
__global__ __launch_bounds__(512) void bucket_csr(const int2* __restrict__ sorted,
                                                  const int* __restrict__ bbase,
                                                  int* __restrict__ rp,
                                                  float* __restrict__ dinv,
                                                  int* __restrict__ csr,
                                                  int n, int E) {
    __shared__ int cnt[512];
    __shared__ int cur[512];
    const int b = blockIdx.x, t = threadIdx.x;
    const int nb0 = b << BSHIFT;
    const int lo = bbase[b], hi = bbase[b + 1];
    cnt[t] = 0;
    __syncthreads();
    for (int k = lo + t; k < hi; k += 512)
        atomicAdd(&cnt[sorted[k].y - nb0], 1);                // LDS atomic
    __syncthreads();
    const int own = cnt[t];
    cur[t] = own;
    __syncthreads();
#pragma unroll
    for (int off = 1; off < 512; off <<= 1) {
        int u = (t >= off) ? cur[t - off] : 0;
        __syncthreads();
        cur[t] += u;
        __syncthreads();
    }
    const int excl = cur[t] - own;
    const int node = nb0 + t;
    if (node < n) {
        rp[node] = lo + excl;
        dinv[node] = rsqrtf((float)(own + 1));
    }
    if (b == 0 && t == 0) rp[n] = E;
    __syncthreads();
    cur[t] = excl;
    __syncthreads();
    for (int k = lo + t; k < hi; k += 512) {
        int2 e = sorted[k];
        int pos = atomicAdd(&cur[e.y - nb0], 1);              // LDS atomic
        csr[lo + pos] = e.x;
    }
}

// ---------------- weight transposes (one launch) ----------------
struct TAll {
    const float* src[9];
    int cum[10];
    int N[9];
    int K[9];
};
__global__ __launch_bounds__(256) void transpose_all(TAll d, bf16* __restrict__ wt, int total) {
    int idx = blockIdx.x * 256 + threadIdx.x;
    if (idx >= total) return;
    int seg = 0;
#pragma unroll
    for (int s = 1; s < 9; ++s) if (idx >= d.cum[s]) seg = s;
    int local = idx - d.cum[seg];
    int N = d.N[seg], K = d.K[seg];
    int k = local / N;
    int nn = local - k * N;
    wt[d.cum[seg] + (size_t)nn * K + k] = (bf16)d.src[seg][local];
}

// ---------------- LDS-layout helpers ----------------
__device__ __forceinline__ void stash_lds(char* H, int ktStride, int r, int c, float v) {
    int kt = c >> 6, w = c & 63;
    int byte = kt * ktStride + r * 128 + (((w >> 3) ^ (r & 7)) * 8 + (w & 7)) * 2;
    *(bf16*)(H + byte) = (bf16)v;
}
__device__ __forceinline__ bf16x8 afrag_lds(const char* H, int ktStride, int kt, int r, int ks, int lane) {
    int ch = (ks * 4 + (lane >> 4)) ^ (r & 7);
    return *(const bf16x8*)(H + kt * ktStride + r * 128 + ch * 16);
}

// ---------------- bf16 MFMA GEMM (conv1..3, post1) ----------------
__global__ __launch_bounds__(256) void gemm_bf16(
    const bf16* __restrict__ A1, int lda1, int K1,
    const bf16* __restrict__ A2, int lda2,
    const bf16* __restrict__ WT,
    const float* __restrict__ bias,
    const float* __restrict__ rowscale,
    void* __restrict__ Cout, int ldc, int M, int Ktot,
    int act, int outf32)
{
    __shared__ bf16 Als[128 * 64];
    __shared__ bf16 Bls[128 * 64];

    const int t = threadIdx.x;
    const int lane = t & 63;
    const int wid = t >> 6;
    const int wm = wid >> 1, wn = wid & 1;
    const int row0 = blockIdx.x * 128;
    const int col0 = blockIdx.y * 128;
    const int nt = Ktot >> 6;

    f32x4 acc[4][4];
#pragma unroll
    for (int mf = 0; mf < 4; ++mf)
#pragma unroll
        for (int nf = 0; nf < 4; ++nf) {
            f32x4 z = {0.f, 0.f, 0.f, 0.f};
            acc[mf][nf] = z;
        }

    int srow[4], scs[4];
#pragma unroll
    for (int i = 0; i < 4; ++i) {
        int ch = wid * 64 + i * 256 + lane;
        int row = ch >> 3, c = ch & 7;
        srow[i] = row;
        scs[i] = (c ^ (row & 7)) * 8;
    }

    for (int kt = 0; kt < nt; ++kt) {
        const int k0 = kt * 64;
        const bf16* Ap; int lda_, kk;
        if (k0 < K1) { Ap = A1; lda_ = lda1; kk = k0; }
        else         { Ap = A2; lda_ = lda2; kk = k0 - K1; }

        __syncthreads();
#pragma unroll
        for (int i = 0; i < 4; ++i) {
            int grow = row0 + srow[i]; if (grow >= M) grow = M - 1;
            const bf16* ga = &Ap[(size_t)grow * lda_ + kk + scs[i]];
            const bf16* gb = &WT[(size_t)(col0 + srow[i]) * Ktot + k0 + scs[i]];
            bf16* la = &Als[(size_t)(wid * 64 + i * 256) * 8];
            bf16* lb = &Bls[(size_t)(wid * 64 + i * 256) * 8];
            __builtin_amdgcn_global_load_lds(
                (const __attribute__((address_space(1))) void*)ga,
                (__attribute__((address_space(3))) void*)la, 16, 0, 0);
            __builtin_amdgcn_global_load_lds(
                (const __attribute__((address_space(1))) void*)gb,
                (__attribute__((address_space(3))) void*)lb, 16, 0, 0);
        }
        asm volatile("s_waitcnt vmcnt(0)" ::: "memory");
        __syncthreads();

#pragma unroll
        for (int ks = 0; ks < 2; ++ks) {
            bf16x8 af[4], bfr[4];
#pragma unroll
            for (int mf = 0; mf < 4; ++mf) {
                int r = wm * 64 + mf * 16 + (lane & 15);
                int ch = (ks * 4 + (lane >> 4)) ^ (r & 7);
                af[mf] = *(const bf16x8*)((const char*)Als + r * 128 + ch * 16);
            }
#pragma unroll
            for (int nf = 0; nf < 4; ++nf) {
                int r = wn * 64 + nf * 16 + (lane & 15);
                int ch = (ks * 4 + (lane >> 4)) ^ (r & 7);
                bfr[nf] = *(const bf16x8*)((const char*)Bls + r * 128 + ch * 16);
            }
#pragma unroll
            for (int mf = 0; mf < 4; ++mf)
#pragma unroll
                for (int nf = 0; nf < 4; ++nf)
                    acc[mf][nf] = __builtin_amdgcn_mfma_f32_16x16x32_bf16(
                        af[mf], bfr[nf], acc[mf][nf], 0, 0, 0);
        }
    }

#pragma unroll
    for (int mf = 0; mf < 4; ++mf) {
        int rbase = row0 + wm * 64 + mf * 16 + (lane >> 4) * 4;
#pragma unroll
        for (int nf = 0; nf < 4; ++nf) {
            int gcol = col0 + wn * 64 + nf * 16 + (lane & 15);
            float bv = bias ? bias[gcol] : 0.f;
#pragma unroll
            for (int i = 0; i < 4; ++i) {
                int grow = rbase + i;
                if (grow >= M) continue;
                float v = acc[mf][nf][i];
                if (rowscale) v *= rowscale[grow];
                v += bv;
                if (act == 1) v = fmaxf(v, 0.f);
                else if (act == 2) v = v > 0.f ? v : 0.1f * v;
                if (outf32) ((float*)Cout)[(size_t)grow * ldc + gcol] = v;
                else        ((bf16*)Cout)[(size_t)grow * ldc + gcol] = (bf16)v;
            }
        }
    }
}

// ---------------- fused_pre: emb = x@W0+b0 ; g = dinv*(emb@Wc0) ----------------
__global__ __launch_bounds__(256) void fused_pre(
    const float* __restrict__ x,
    const bf16* __restrict__ preWT,
    const float* __restrict__ pre_b,
    const bf16* __restrict__ c0WT,
    const float* __restrict__ dinv,
    bf16* __restrict__ emb, int lde,
    bf16* __restrict__ g, int M)
{
    __shared__ char lds[49152];
    bf16* Hbuf = (bf16*)lds;
    bf16* Bls  = (bf16*)(lds + 32768);
    bf16* Als  = Hbuf;

    const int t = threadIdx.x;
    const int lane = t & 63;
    const int wid = t >> 6;
    const int wm = wid >> 1, wn = wid & 1;
    const int row0 = blockIdx.x * 128;

    int srow[4], scs[4];
#pragma unroll
    for (int i = 0; i < 4; ++i) {
        int ch = wid * 64 + i * 256 + lane;
        int row = ch >> 3, c = ch & 7;
        srow[i] = row;
        scs[i] = (c ^ (row & 7)) * 8;
    }

    f32x4 acc[4][4];
#pragma unroll
    for (int mf = 0; mf < 4; ++mf)
#pragma unroll
        for (int nf = 0; nf < 4; ++nf) { f32x4 z = {0,0,0,0}; acc[mf][nf] = z; }

    for (int kt = 0; kt < 2; ++kt) {
        __syncthreads();
#pragma unroll
        for (int i = 0; i < 4; ++i) {
            int grow = row0 + srow[i]; if (grow >= M) grow = M - 1;
            const float* gx = &x[(size_t)grow * 128 + kt * 64 + scs[i]];
            float4 f0 = *(const float4*)gx;
            float4 f1 = *(const float4*)(gx + 4);
            bf16x8 av = {(bf16)f0.x, (bf16)f0.y, (bf16)f0.z, (bf16)f0.w,
                         (bf16)f1.x, (bf16)f1.y, (bf16)f1.z, (bf16)f1.w};
            *(bf16x8*)((char*)Als + (size_t)(wid * 64 + i * 256 + lane) * 16) = av;
            const bf16* gb = &preWT[(size_t)srow[i] * 128 + kt * 64 + scs[i]];
            bf16* lb = &Bls[(size_t)(wid * 64 + i * 256) * 8];
            __builtin_amdgcn_global_load_lds(
                (const __attribute__((address_space(1))) void*)gb,
                (__attribute__((address_space(3))) void*)lb, 16, 0, 0);
        }
        asm volatile("s_waitcnt vmcnt(0)" ::: "memory");
        __syncthreads();
#pragma unroll
        for (int ks = 0; ks < 2; ++ks) {
            bf16x8 af[4], bfr[4];
#pragma unroll
            for (int mf = 0; mf < 4; ++mf) {
                int r = wm * 64 + mf * 16 + (lane & 15);
                int ch = (ks * 4 + (lane >> 4)) ^ (r & 7);
                af[mf] = *(const bf16x8*)((const char*)Als + r * 128 + ch * 16);
            }
#pragma unroll
            for (int nf = 0; nf < 4; ++nf) {
                int r = wn * 64 + nf * 16 + (lane & 15);
                int ch = (ks * 4 + (lane >> 4)) ^ (r & 7);
                bfr[nf] = *(const bf16x8*)((const char*)Bls + r * 128 + ch * 16);
            }
#pragma unroll
            for (int mf = 0; mf < 4; ++mf)
#pragma unroll
                for (int nf = 0; nf < 4; ++nf)
                    acc[mf][nf] = __builtin_amdgcn_mfma_f32_16x16x32_bf16(
                        af[mf], bfr[nf], acc[mf][nf], 0, 0, 0);
        }
    }
    __syncthreads();

#pragma unroll
    for (int mf = 0; mf < 4; ++mf) {
        int rl = wm * 64 + mf * 16 + (lane >> 4) * 4;
#pragma unroll
        for (int nf = 0; nf < 4; ++nf) {
            int c = wn * 64 + nf * 16 + (lane & 15);
            float bv = pre_b[c];
#pragma unroll
            for (int i = 0; i < 4; ++i) {
                int r = rl + i;
                float v = acc[mf][nf][i] + bv;
                stash_lds((char*)Hbuf, 16384, r, c, v);
                int grow = row0 + r;
                if (grow < M) emb[(size_t)grow * lde + c] = (bf16)v;
            }
        }
    }

#pragma unroll
    for (int mf = 0; mf < 4; ++mf)
#pragma unroll
        for (int nf = 0; nf < 4; ++nf) { f32x4 z = {0,0,0,0}; acc[mf][nf] = z; }

    for (int kt = 0; kt < 2; ++kt) {
        __syncthreads();
#pragma unroll
        for (int i = 0; i < 4; ++i) {
            const bf16* gb = &c0WT[(size_t)srow[i] * 128 + kt * 64 + scs[i]];
            bf16* lb = &Bls[(size_t)(wid * 64 + i * 256) * 8];
            __builtin_amdgcn_global_load_lds(
                (const __attribute__((address_space(1))) void*)gb,
                (__attribute__((address_space(3))) void*)lb, 16, 0, 0);
        }
        asm volatile("s_waitcnt vmcnt(0)" ::: "memory");
        __syncthreads();
#pragma unroll
        for (int ks = 0; ks < 2; ++ks) {
            bf16x8 af[4], bfr[4];
#pragma unroll
            for (int mf = 0; mf < 4; ++mf) {
                int r = wm * 64 + mf * 16 + (lane & 15);
                af[mf] = afrag_lds((const char*)Hbuf, 16384, kt, r, ks, lane);
            }
#pragma unroll
            for (int nf = 0; nf < 4; ++nf) {
                int r = wn * 64 + nf * 16 + (lane & 15);
                int ch = (ks * 4 + (lane >> 4)) ^ (r & 7);
                bfr[nf] = *(const bf16x8*)((const char*)Bls + r * 128 + ch * 16);
            }
#pragma unroll
            for (int mf = 0; mf < 4; ++mf)
#pragma unroll
                for (int nf = 0; nf < 4; ++nf)
                    acc[mf][nf] = __builtin_amdgcn_mfma_f32_16x16x32_bf16(
                        af[mf], bfr[nf], acc[mf][nf], 0, 0, 0);
        }
    }

#pragma unroll
    for (int mf = 0; mf < 4; ++mf) {
        int rbase = row0 + wm * 64 + mf * 16 + (lane >> 4) * 4;
#pragma unroll
        for (int nf = 0; nf < 4; ++nf) {
            int c = wn * 64 + nf * 16 + (lane & 15);
#pragma unroll
            for (int i = 0; i < 4; ++i) {
                int grow = rbase + i;
                if (grow >= M) continue;
                g[(size_t)grow * 128 + c] = (bf16)(acc[mf][nf][i] * dinv[grow]);
            }
        }
    }
}

// ---------------- fused_post: h1 -> h2 -> h3 -> out (64-row tile) ----------------
__global__ __launch_bounds__(256) void fused_post(
    const bf16* __restrict__ h1,
    const bf16* __restrict__ W2T,
    const float* __restrict__ b2,
    const bf16* __restrict__ W3T,
    const float* __restrict__ b3,
    const bf16* __restrict__ W4T,
    const float* __restrict__ b4,
    float* __restrict__ out, int M)
{
    __shared__ char lds[49152];
    bf16* H2  = (bf16*)lds;
    bf16* Bls = (bf16*)(lds + 16384);
    bf16* H3  = (bf16*)(lds + 32768);
    bf16* Als = H3;

    const int t = threadIdx.x;
    const int lane = t & 63;
    const int wid = t >> 6;
    const int wm = wid >> 1, wn = wid & 1;
    const int row0 = blockIdx.x * 64;

    int srow[4], scs[4];
#pragma unroll
    for (int i = 0; i < 4; ++i) {
        int ch = wid * 64 + i * 256 + lane;
        int row = ch >> 3, c = ch & 7;
        srow[i] = row;
        scs[i] = (c ^ (row & 7)) * 8;
    }

    f32x4 acc[2][4], acc3[2][4];
#pragma unroll
    for (int mf = 0; mf < 2; ++mf)
#pragma unroll
        for (int nf = 0; nf < 4; ++nf) {
            f32x4 z = {0,0,0,0};
            acc[mf][nf] = z;
            acc3[mf][nf] = z;
        }

    for (int kt = 0; kt < 2; ++kt) {
        __syncthreads();
#pragma unroll
        for (int i = 0; i < 2; ++i) {
            int grow = row0 + srow[i]; if (grow >= M) grow = M - 1;
            const bf16* ga = &h1[(size_t)grow * 128 + kt * 64 + scs[i]];
            bf16* la = &Als[(size_t)(wid * 64 + i * 256) * 8];
            __builtin_amdgcn_global_load_lds(
                (const __attribute__((address_space(1))) void*)ga,
                (__attribute__((address_space(3))) void*)la, 16, 0, 0);
        }
#pragma unroll
        for (int i = 0; i < 4; ++i) {
            const bf16* gb = &W2T[(size_t)srow[i] * 128 + kt * 64 + scs[i]];
            bf16* lb = &Bls[(size_t)(wid * 64 + i * 256) * 8];
            __builtin_amdgcn_global_load_lds(
                (const __attribute__((address_space(1))) void*)gb,
                (__attribute__((address_space(3))) void*)lb, 16, 0, 0);
        }
        asm volatile("s_waitcnt vmcnt(0)" ::: "memory");
        __syncthreads();
#pragma unroll
        for (int ks = 0; ks < 2; ++ks) {
            bf16x8 af[2], bfr[4];
#pragma unroll
            for (int mf = 0; mf < 2; ++mf) {
                int r = wm * 32 + mf * 16 + (lane & 15);
                int ch = (ks * 4 + (lane >> 4)) ^ (r & 7);
                af[mf] = *(const bf16x8*)((const char*)Als + r * 128 + ch * 16);
            }
#pragma unroll
            for (int nf = 0; nf < 4; ++nf) {
                int r = wn * 64 + nf * 16 + (lane & 15);
                int ch = (ks * 4 + (lane >> 4)) ^ (r & 7);
                bfr[nf] = *(const bf16x8*)((const char*)Bls + r * 128 + ch * 16);
            }
#pragma unroll
            for (int mf = 0; mf < 2; ++mf)
#pragma unroll
                for (int nf = 0; nf < 4; ++nf)
                    acc[mf][nf] = __builtin_amdgcn_mfma_f32_16x16x32_bf16(
                        af[mf], bfr[nf], acc[mf][nf], 0, 0, 0);
        }
    }
    __syncthreads();
#pragma unroll
    for (int mf = 0; mf < 2; ++mf) {
        int rl = wm * 32 + mf * 16 + (lane >> 4) * 4;
#pragma unroll
        for (int nf = 0; nf < 4; ++nf) {
            int c = wn * 64 + nf * 16 + (lane & 15);
            float bv = b2[c];
#pragma unroll
            for (int i = 0; i < 4; ++i)
                stash_lds((char*)H2, 8192, rl + i, c, fmaxf(acc[mf][nf][i] + bv, 0.f));
        }
    }

    for (int hh = 0; hh < 2; ++hh) {
#pragma unroll
        for (int mf = 0; mf < 2; ++mf)
#pragma unroll
            for (int nf = 0; nf < 4; ++nf) { f32x4 z = {0,0,0,0}; acc[mf][nf] = z; }
        for (int kt = 0; kt < 2; ++kt) {
            __syncthreads();
#pragma unroll
            for (int i = 0; i < 4; ++i) {
                const bf16* gb = &W3T[(size_t)(hh * 128 + srow[i]) * 128 + kt * 64 + scs[i]];
                bf16* lb = &Bls[(size_t)(wid * 64 + i * 256) * 8];
                __builtin_amdgcn_global_load_lds(
                    (const __attribute__((address_space(1))) void*)gb,
                    (__attribute__((address_space(3))) void*)lb, 16, 0, 0);
            }
            asm volatile("s_waitcnt vmcnt(0)" ::: "memory");
            __syncthreads();
#pragma unroll
            for (int ks = 0; ks < 2; ++ks) {
                bf16x8 af[2], bfr[4];
#pragma unroll
                for (int mf = 0; mf < 2; ++mf) {
                    int r = wm * 32 + mf * 16 + (lane & 15);
                    af[mf] = afrag_lds((const char*)H2, 8192, kt, r, ks, lane);
                }
#pragma unroll
                for (int nf = 0; nf < 4; ++nf) {
                    int r = wn * 64 + nf * 16 + (lane & 15);
                    int ch = (ks * 4 + (lane >> 4)) ^ (r & 7);
                    bfr[nf] = *(const bf16x8*)((const char*)Bls + r * 128 + ch * 16);
                }
#pragma unroll
                for (int mf = 0; mf < 2; ++mf)
#pragma unroll
                    for (int nf = 0; nf < 4; ++nf)
                        acc[mf][nf] = __builtin_amdgcn_mfma_f32_16x16x32_bf16(
                            af[mf], bfr[nf], acc[mf][nf], 0, 0, 0);
            }
        }
        __syncthreads();
#pragma unroll
        for (int mf = 0; mf < 2; ++mf) {
            int rl = wm * 32 + mf * 16 + (lane >> 4) * 4;
#pragma unroll
            for (int nf = 0; nf < 4; ++nf) {
                int c = wn * 64 + nf * 16 + (lane & 15);
                float bv = b3[hh * 128 + c];
#pragma unroll
                for (int i = 0; i < 4; ++i)
                    stash_lds((char*)H3, 8192, rl + i, c, fmaxf(acc[mf][nf][i] + bv, 0.f));
            }
        }
        for (int kt = 0; kt < 2; ++kt) {
            __syncthreads();
#pragma unroll
            for (int i = 0; i < 4; ++i) {
                const bf16* gb = &W4T[(size_t)srow[i] * 256 + hh * 128 + kt * 64 + scs[i]];
                bf16* lb = &Bls[(size_t)(wid * 64 + i * 256) * 8];
                __builtin_amdgcn_global_load_lds(
                    (const __attribute__((address_space(1))) void*)gb,
                    (__attribute__((address_space(3))) void*)lb, 16, 0, 0);
            }
            asm volatile("s_waitcnt vmcnt(0)" ::: "memory");
            __syncthreads();
#pragma unroll
            for (int ks = 0; ks < 2; ++ks) {
                bf16x8 af[2], bfr[4];
#pragma unroll
                for (int mf = 0; mf < 2; ++mf) {
                    int r = wm * 32 + mf * 16 + (lane & 15);
                    af[mf] = afrag_lds((const char*)H3, 8192, kt, r, ks, lane);
                }
#pragma unroll
                for (int nf = 0; nf < 4; ++nf) {
                    int r = wn * 64 + nf * 16 + (lane & 15);
                    int ch = (ks * 4 + (lane >> 4)) ^ (r & 7);
                    bfr[nf] = *(const bf16x8*)((const char*)Bls + r * 128 + ch * 16);
                }
#pragma unroll
                for (int mf = 0; mf < 2; ++mf)
#pragma unroll
                    for (int nf = 0; nf < 4; ++nf)
                        acc3[mf][nf] = __builtin_amdgcn_mfma_f32_16x16x32_bf16(
                            af[mf], bfr[nf], acc3[mf][nf], 0, 0, 0);
            }
        }
    }

#pragma unroll
    for (int mf = 0; mf < 2; ++mf) {
        int rbase = row0 + wm * 32 + mf * 16 + (lane >> 4) * 4;
#pragma unroll
        for (int nf = 0; nf < 4; ++nf) {
            int c = wn * 64 + nf * 16 + (lane & 15);
            float bv = b4[c];
#pragma unroll
            for (int i = 0; i < 4; ++i) {
                int grow = rbase + i;
                if (grow < M) out[(size_t)grow * 128 + c] = acc3[mf][nf][i] + bv;
            }
        }
    }
}

// ---------------- fused gather ----------------
__global__ __launch_bounds__(256) void gcn_gather(
    const int* __restrict__ rp, const int* __restrict__ csr,
    const bf16* __restrict__ g, const float* __restrict__ dinv,
    const float* __restrict__ b,
    bf16* __restrict__ out, int ldo, int n)
{
    const int node = (int)(((long long)blockIdx.x * 256 + threadIdx.x) >> 6);
    if (node >= n) return;
    const int lane = threadIdx.x & 63;
    const int grp = lane >> 4;
    const int cc = lane & 15;
    const int start = rp[node];
    const int end = rp[node + 1];

    float acc[8];
#pragma unroll
    for (int j = 0; j < 8; ++j) acc[j] = 0.f;

    int j = start + grp;
    for (; j + 12 < end; j += 16) {
        int s0 = csr[j];
        int s1 = csr[j + 4];
        int s2 = csr[j + 8];
        int s3 = csr[j + 12];
        bf16x8 v0 = *(const bf16x8*)&g[(size_t)s0 * 128 + cc * 8];
        bf16x8 v1 = *(const bf16x8*)&g[(size_t)s1 * 128 + cc * 8];
        bf16x8 v2 = *(const bf16x8*)&g[(size_t)s2 * 128 + cc * 8];
        bf16x8 v3 = *(const bf16x8*)&g[(size_t)s3 * 128 + cc * 8];
#pragma unroll
        for (int jj = 0; jj < 8; ++jj)
            acc[jj] += ((float)v0[jj] + (float)v1[jj]) + ((float)v2[jj] + (float)v3[jj]);
    }
    for (; j < end; j += 4) {
        int s0 = csr[j];
        bf16x8 v0 = *(const bf16x8*)&g[(size_t)s0 * 128 + cc * 8];
#pragma unroll
        for (int jj = 0; jj < 8; ++jj) acc[jj] += (float)v0[jj];
    }
#pragma unroll
    for (int jj = 0; jj < 8; ++jj) {
        acc[jj] += __shfl_xor(acc[jj], 16, 64);
        acc[jj] += __shfl_xor(acc[jj], 32, 64);
    }
    if (grp == 0) {
        bf16x8 sv = *(const bf16x8*)&g[(size_t)node * 128 + cc * 8];
        float s = dinv[node];
        bf16x8 o;
#pragma unroll
        for (int jj = 0; jj < 8; ++jj) {
            float v = fmaf(s, acc[jj] + (float)sv[jj], b[cc * 8 + jj]);
            o[jj] = (bf16)fmaxf(v, 0.f);
        }
        *(bf16x8*)&out[(size_t)node * ldo + cc * 8] = o;
    }
}

// ---------------- launcher ----------------
extern "C" void kernel_launch(void* const* d_in, const int* in_sizes, int n_in,
                              void* d_out, int out_size, void* d_ws, size_t ws_size,
                              hipStream_t stream) {
    const float* x      = (const float*)d_in[0];
    const int*   ei     = (const int*)d_in[1];
    const float* pre_w  = (const float*)d_in[2];
    const float* pre_b  = (const float*)d_in[3];
    const float* conv_w[4] = {(const float*)d_in[4], (const float*)d_in[6],
                              (const float*)d_in[8], (const float*)d_in[10]};
    const float* conv_b[4] = {(const float*)d_in[5], (const float*)d_in[7],
                              (const float*)d_in[9], (const float*)d_in[11]};
    const float* post_w1 = (const float*)d_in[12];
    const float* post_b1 = (const float*)d_in[13];
    const float* post_w2 = (const float*)d_in[14];
    const float* post_b2 = (const float*)d_in[15];
    const float* post_w3 = (const float*)d_in[16];
    const float* post_b3 = (const float*)d_in[17];
    const float* post_w4 = (const float*)d_in[18];
    const float* post_b4 = (const float*)d_in[19];

    const int n = in_sizes[0] / 128;        // 100000
    const int E = in_sizes[1] / 2;          // 1600000
    const int NBKT = (n + 511) >> BSHIFT;   // 196 buckets
    const int NBLK = (E + PCHUNK - 1) / PCHUNK;  // 391 partition blocks

    // ws layout (bytes)
    size_t off = 0;
    bf16* emb  = (bf16*)((char*)d_ws + off); off += (size_t)n * 512 * 2;
    bf16* g    = (bf16*)((char*)d_ws + off); off += (size_t)n * 128 * 2;
    bf16* h4   = (bf16*)((char*)d_ws + off); off += (size_t)n * 128 * 2;
    float* dinv = (float*)((char*)d_ws + off); off += (size_t)n * 4;
    int*   rp   = (int*)((char*)d_ws + off); off += (size_t)(n + 4) * 4;
    int*   csr  = (int*)((char*)d_ws + off); off += (size_t)E * 4;
    int2*  sorted = (int2*)((char*)d_ws + off); off += (size_t)E * 8;
    bf16*  wt   = (bf16*)((char*)d_ws + off); off += (size_t)344064 * 2;
    int*   bcountT = (int*)((char*)d_ws + off); off += (size_t)NBKT * NBLK * 4;
    int*   btot    = (int*)((char*)d_ws + off); off += (size_t)NBKT * 4;
    int*   bbase   = (int*)((char*)d_ws + off); off += (size_t)(NBKT + 1) * 4;
    if (ws_size < off) return;  // diagnostic early-out

    bf16* h1 = g;               // post1 output overlays g (dead after gather3)

    // weight-pool offsets (elements)
    bf16* pre_wt  = wt;            // [128][128]
    bf16* c_wt0   = wt + 16384;
    bf16* c_wt1   = wt + 32768;
    bf16* c_wt2   = wt + 65536;
    bf16* c_wt3   = wt + 114688;
    bf16* p1_wt   = wt + 180224;   // [128][640]
    bf16* p2_wt   = wt + 262144;
    bf16* p3_wt   = wt + 278528;   // [256][128]
    bf16* p4_wt   = wt + 311296;   // [128][256]
    bf16* c_wt[4] = {c_wt0, c_wt1, c_wt2, c_wt3};

    // ---- CSR build: bucket partition (no global atomics) ----
    part_count<<<NBLK, 256, 0, stream>>>(ei, bcountT, NBKT, NBLK, E);
    part_scanb<<<NBKT, 256, 0, stream>>>(bcountT, btot, NBLK);
    part_scant<<<1, 256, 0, stream>>>(btot, bbase, NBKT, E);
    part_scatter<<<NBLK, 256, 0, stream>>>(ei, bcountT, bbase, sorted, NBKT, NBLK, E);
    bucket_csr<<<NBKT, 512, 0, stream>>>(sorted, bbase, rp, dinv, csr, n, E);

    // ---- all weight transposes in one launch ----
    TAll ta;
    ta.src[0] = pre_w;   ta.K[0] = 128; ta.N[0] = 128;
    ta.src[1] = conv_w[0]; ta.K[1] = 128; ta.N[1] = 128;
    ta.src[2] = conv_w[1]; ta.K[2] = 256; ta.N[2] = 128;
    ta.src[3] = conv_w[2]; ta.K[3] = 384; ta.N[3] = 128;
    ta.src[4] = conv_w[3]; ta.K[4] = 512; ta.N[4] = 128;
    ta.src[5] = post_w1;  ta.K[5] = 640; ta.N[5] = 128;
    ta.src[6] = post_w2;  ta.K[6] = 128; ta.N[6] = 128;
    ta.src[7] = post_w3;  ta.K[7] = 128; ta.N[7] = 256;
    ta.src[8] = post_w4;  ta.K[8] = 256; ta.N[8] = 128;
    ta.cum[0] = 0;
    for (int s = 0; s < 9; ++s) ta.cum[s + 1] = ta.cum[s] + ta.K[s] * ta.N[s];
    const int wtot = ta.cum[9];   // 344064
    transpose_all<<<(wtot + 255) / 256, 256, 0, stream>>>(ta, wt, wtot);

    const int gx = (n + 127) / 128;   // 782
    const int gx2 = (n + 63) / 64;    // 1563
    auto gemm = [&](const bf16* A1, int lda1, int K1, const bf16* A2, int lda2,
                    const bf16* WT, const float* bias, const float* rs,
                    void* C, int ldc, int Ktot, int N, int act, int outf32) {
        dim3 grid(gx, N / 128);
        gemm_bf16<<<grid, 256, 0, stream>>>(A1, lda1, K1, A2, lda2, WT, bias, rs,
                                            C, ldc, n, Ktot, act, outf32);
    };

    const int ggrid = (int)(((long long)n * 64 + 255) / 256);
    for (int l = 0; l < 4; ++l) {
        if (l == 0) {
            fused_pre<<<gx, 256, 0, stream>>>(x, pre_wt, pre_b, c_wt0, dinv,
                                              emb, 512, g, n);
        } else {
            int K = 128 * (l + 1);
            gemm(emb, 512, K, emb, 512, c_wt[l], nullptr, dinv, g, 128, K, 128, 0, 0);
        }
        bf16* out = (l < 3) ? (emb + (size_t)128 * (l + 1)) : h4;
        int ldo = (l < 3) ? 512 : 128;
        gcn_gather<<<ggrid, 256, 0, stream>>>(rp, csr, g, dinv, conv_b[l], out, ldo, n);
    }

    // post_mp
    gemm(emb, 512, 512, h4, 128, p1_wt, post_b1, nullptr, h1, 128, 640, 128, 2, 0);
    fused_post<<<gx2, 256, 0, stream>>>(h1, p2_wt, post_b2, p3_wt, post_b3,
                                        p4_wt, post_b4, (float*)d_out, n);
}

// Round 12
// 592.122 us; speedup vs baseline: 1.3668x; 1.0264x over previous
//
#include <hip/hip_runtime.h>

// ---------------------------------------------------------------------------
// GeneralGNN: 4-layer GCN (skip='all') + MLP head.
// Round 12: post-MLP fully fused into ONE kernel (h1 never touches HBM):
//   stage0: h1 = LeakyReLU([emb|h4] @ W1^T + b1)   (K=640, dual-source A)
//   stage1: h2 = relu(h1 @ W2^T + b2)              (h1 in LDS)
//   stage2/3 (x2 halves): h3 = relu(h2@W3+b3); out += h3@W4    (LDS)
// LDS 48KB via overlays: H1@0 (H3 reuses after stage1), Astage@32K (H2
// reuses after stage1 epilogue). Gather left untouched (at NXCD*|g| fetch
// floor, 2.9-3.4 TB/s fabric ceiling, ILP was null in r6).
// ---------------------------------------------------------------------------

typedef __bf16 bf16;
typedef __attribute__((ext_vector_type(8))) __bf16 bf16x8;
typedef __attribute__((ext_vector_type(4))) float f32x4;

#define BSHIFT 9                 // bucket = dst >> 9  (512 nodes/bucket)
#define PCHUNK 4096              // edges per partition block

// ---- Pass A: per-(bucket, block) counts; no global atomics ----
__global__ __launch_bounds__(256) void part_count(const int* __restrict__ ei,
                                                  int* __restrict__ bcountT,
                                                  int NBKT, int NBLK, int E) {
    __shared__ int cnt[256];
    const int t = threadIdx.x, blk = blockIdx.x;
    if (t < NBKT) cnt[t] = 0;
    __syncthreads();
    const int base = blk * PCHUNK;
#pragma unroll
    for (int i = 0; i < 16; ++i) {
        int e = base + i * 256 + t;
        if (e < E) atomicAdd(&cnt[ei[E + e] >> BSHIFT], 1);   // LDS atomic
    }
    __syncthreads();
    if (t < NBKT) bcountT[t * NBLK + blk] = cnt[t];
}

// ---- Pass B: per-bucket exclusive scan of its row (across blocks) ----
__global__ __launch_bounds__(256) void part_scanb(int* __restrict__ bcountT,
                                                  int* __restrict__ btot, int NBLK) {
    __shared__ int sums[256];
    const int b = blockIdx.x, t = threadIdx.x;
    int* row = &bcountT[(size_t)b * NBLK];
    const int chunk = (NBLK + 255) / 256;
    const int lo = t * chunk, hi = min(lo + chunk, NBLK);
    int s = 0;
    for (int i = lo; i < hi; ++i) s += row[i];
    sums[t] = s;
    __syncthreads();
#pragma unroll
    for (int off = 1; off < 256; off <<= 1) {
        int u = (t >= off) ? sums[t - off] : 0;
        __syncthreads();
        sums[t] += u;
        __syncthreads();
    }
    int run = sums[t] - s;
    for (int i = lo; i < hi; ++i) { int c = row[i]; row[i] = run; run += c; }
    if (t == 255) btot[b] = sums[255];
}

// ---- Pass B2: bucket bases (exclusive scan of btot); bbase[NBKT] = E ----
__global__ __launch_bounds__(256) void part_scant(const int* __restrict__ btot,
                                                  int* __restrict__ bbase, int NBKT, int E) {
    __shared__ int sums[256];
    const int t = threadIdx.x;
    int s = (t < NBKT) ? btot[t] : 0;
    sums[t] = s;
    __syncthreads();
#pragma unroll
    for (int off = 1; off < 256; off <<= 1) {
        int u = (t >= off) ? sums[t - off] : 0;
        __syncthreads();
        sums[t] += u;
        __syncthreads();
    }
    if (t < NBKT) bbase[t] = sums[t] - s;
    if (t == 0) bbase[NBKT] = E;
}

// ---- Pass C: scatter edges to bucket-sorted order ----
__global__ __launch_bounds__(256) void part_scatter(const int* __restrict__ ei,
                                                    const int* __restrict__ bcountT,
                                                    const int* __restrict__ bbase,
                                                    int2* __restrict__ sorted,
                                                    int NBKT, int NBLK, int E) {
    __shared__ int cur[256];
    const int t = threadIdx.x, blk = blockIdx.x;
    if (t < NBKT) cur[t] = bbase[t] + bcountT[(size_t)t * NBLK + blk];
    __syncthreads();
    const int base = blk * PCHUNK;
#pragma unroll
    for (int i = 0; i < 16; ++i) {
        int e = base + i * 256 + t;
        if (e < E) {
            int src = ei[e], dst = ei[E + e];
            int pos = atomicAdd(&cur[dst >> BSHIFT], 1);      // LDS atomic
            sorted[pos] = make_int2(src, dst);
        }
    }
}

// ---- Pass D: per-bucket CSR rows + rp + dinv (all traffic L2-local) ----
__global__ __launch_bounds__(512) void bucket_csr(const int2* __restrict__ sorted,
                                                  const int* __restrict__ bbase,
                                                  int* __restrict__ rp,
                                                  float* __restrict__ dinv,
                                                  int* __restrict__ csr,
                                                  int n, int E) {
    __shared__ int cnt[512];
    __shared__ int cur[512];
    const int b = blockIdx.x, t = threadIdx.x;
    const int nb0 = b << BSHIFT;
    const int lo = bbase[b], hi = bbase[b + 1];
    cnt[t] = 0;
    __syncthreads();
    for (int k = lo + t; k < hi; k += 512)
        atomicAdd(&cnt[sorted[k].y - nb0], 1);                // LDS atomic
    __syncthreads();
    const int own = cnt[t];
    cur[t] = own;
    __syncthreads();
#pragma unroll
    for (int off = 1; off < 512; off <<= 1) {
        int u = (t >= off) ? cur[t - off] : 0;
        __syncthreads();
        cur[t] += u;
        __syncthreads();
    }
    const int excl = cur[t] - own;
    const int node = nb0 + t;
    if (node < n) {
        rp[node] = lo + excl;
        dinv[node] = rsqrtf((float)(own + 1));
    }
    if (b == 0 && t == 0) rp[n] = E;
    __syncthreads();
    cur[t] = excl;
    __syncthreads();
    for (int k = lo + t; k < hi; k += 512) {
        int2 e = sorted[k];
        int pos = atomicAdd(&cur[e.y - nb0], 1);              // LDS atomic
        csr[lo + pos] = e.x;
    }
}

// ---------------- weight transposes (one launch) ----------------
struct TAll {
    const float* src[9];
    int cum[10];
    int N[9];
    int K[9];
};
__global__ __launch_bounds__(256) void transpose_all(TAll d, bf16* __restrict__ wt, int total) {
    int idx = blockIdx.x * 256 + threadIdx.x;
    if (idx >= total) return;
    int seg = 0;
#pragma unroll
    for (int s = 1; s < 9; ++s) if (idx >= d.cum[s]) seg = s;
    int local = idx - d.cum[seg];
    int N = d.N[seg], K = d.K[seg];
    int k = local / N;
    int nn = local - k * N;
    wt[d.cum[seg] + (size_t)nn * K + k] = (bf16)d.src[seg][local];
}

// ---------------- LDS-layout helpers ----------------
__device__ __forceinline__ void stash_lds(char* H, int ktStride, int r, int c, float v) {
    int kt = c >> 6, w = c & 63;
    int byte = kt * ktStride + r * 128 + (((w >> 3) ^ (r & 7)) * 8 + (w & 7)) * 2;
    *(bf16*)(H + byte) = (bf16)v;
}
__device__ __forceinline__ bf16x8 afrag_lds(const char* H, int ktStride, int kt, int r, int ks, int lane) {
    int ch = (ks * 4 + (lane >> 4)) ^ (r & 7);
    return *(const bf16x8*)(H + kt * ktStride + r * 128 + ch * 16);
}

// ---------------- bf16 MFMA GEMM (conv1..3) ----------------
__global__ __launch_bounds__(256) void gemm_bf16(
    const bf16* __restrict__ A1, int lda1, int K1,
    const bf16* __restrict__ A2, int lda2,
    const bf16* __restrict__ WT,
    const float* __restrict__ bias,
    const float* __restrict__ rowscale,
    void* __restrict__ Cout, int ldc, int M, int Ktot,
    int act, int outf32)
{
    __shared__ bf16 Als[128 * 64];
    __shared__ bf16 Bls[128 * 64];

    const int t = threadIdx.x;
    const int lane = t & 63;
    const int wid = t >> 6;
    const int wm = wid >> 1, wn = wid & 1;
    const int row0 = blockIdx.x * 128;
    const int col0 = blockIdx.y * 128;
    const int nt = Ktot >> 6;

    f32x4 acc[4][4];
#pragma unroll
    for (int mf = 0; mf < 4; ++mf)
#pragma unroll
        for (int nf = 0; nf < 4; ++nf) {
            f32x4 z = {0.f, 0.f, 0.f, 0.f};
            acc[mf][nf] = z;
        }

    int srow[4], scs[4];
#pragma unroll
    for (int i = 0; i < 4; ++i) {
        int ch = wid * 64 + i * 256 + lane;
        int row = ch >> 3, c = ch & 7;
        srow[i] = row;
        scs[i] = (c ^ (row & 7)) * 8;
    }

    for (int kt = 0; kt < nt; ++kt) {
        const int k0 = kt * 64;
        const bf16* Ap; int lda_, kk;
        if (k0 < K1) { Ap = A1; lda_ = lda1; kk = k0; }
        else         { Ap = A2; lda_ = lda2; kk = k0 - K1; }

        __syncthreads();
#pragma unroll
        for (int i = 0; i < 4; ++i) {
            int grow = row0 + srow[i]; if (grow >= M) grow = M - 1;
            const bf16* ga = &Ap[(size_t)grow * lda_ + kk + scs[i]];
            const bf16* gb = &WT[(size_t)(col0 + srow[i]) * Ktot + k0 + scs[i]];
            bf16* la = &Als[(size_t)(wid * 64 + i * 256) * 8];
            bf16* lb = &Bls[(size_t)(wid * 64 + i * 256) * 8];
            __builtin_amdgcn_global_load_lds(
                (const __attribute__((address_space(1))) void*)ga,
                (__attribute__((address_space(3))) void*)la, 16, 0, 0);
            __builtin_amdgcn_global_load_lds(
                (const __attribute__((address_space(1))) void*)gb,
                (__attribute__((address_space(3))) void*)lb, 16, 0, 0);
        }
        asm volatile("s_waitcnt vmcnt(0)" ::: "memory");
        __syncthreads();

#pragma unroll
        for (int ks = 0; ks < 2; ++ks) {
            bf16x8 af[4], bfr[4];
#pragma unroll
            for (int mf = 0; mf < 4; ++mf) {
                int r = wm * 64 + mf * 16 + (lane & 15);
                int ch = (ks * 4 + (lane >> 4)) ^ (r & 7);
                af[mf] = *(const bf16x8*)((const char*)Als + r * 128 + ch * 16);
            }
#pragma unroll
            for (int nf = 0; nf < 4; ++nf) {
                int r = wn * 64 + nf * 16 + (lane & 15);
                int ch = (ks * 4 + (lane >> 4)) ^ (r & 7);
                bfr[nf] = *(const bf16x8*)((const char*)Bls + r * 128 + ch * 16);
            }
#pragma unroll
            for (int mf = 0; mf < 4; ++mf)
#pragma unroll
                for (int nf = 0; nf < 4; ++nf)
                    acc[mf][nf] = __builtin_amdgcn_mfma_f32_16x16x32_bf16(
                        af[mf], bfr[nf], acc[mf][nf], 0, 0, 0);
        }
    }

#pragma unroll
    for (int mf = 0; mf < 4; ++mf) {
        int rbase = row0 + wm * 64 + mf * 16 + (lane >> 4) * 4;
#pragma unroll
        for (int nf = 0; nf < 4; ++nf) {
            int gcol = col0 + wn * 64 + nf * 16 + (lane & 15);
            float bv = bias ? bias[gcol] : 0.f;
#pragma unroll
            for (int i = 0; i < 4; ++i) {
                int grow = rbase + i;
                if (grow >= M) continue;
                float v = acc[mf][nf][i];
                if (rowscale) v *= rowscale[grow];
                v += bv;
                if (act == 1) v = fmaxf(v, 0.f);
                else if (act == 2) v = v > 0.f ? v : 0.1f * v;
                if (outf32) ((float*)Cout)[(size_t)grow * ldc + gcol] = v;
                else        ((bf16*)Cout)[(size_t)grow * ldc + gcol] = (bf16)v;
            }
        }
    }
}

// ---------------- fused_pre: emb = x@W0+b0 ; g = dinv*(emb@Wc0) ----------------
__global__ __launch_bounds__(256) void fused_pre(
    const float* __restrict__ x,
    const bf16* __restrict__ preWT,
    const float* __restrict__ pre_b,
    const bf16* __restrict__ c0WT,
    const float* __restrict__ dinv,
    bf16* __restrict__ emb, int lde,
    bf16* __restrict__ g, int M)
{
    __shared__ char lds[49152];
    bf16* Hbuf = (bf16*)lds;
    bf16* Bls  = (bf16*)(lds + 32768);
    bf16* Als  = Hbuf;

    const int t = threadIdx.x;
    const int lane = t & 63;
    const int wid = t >> 6;
    const int wm = wid >> 1, wn = wid & 1;
    const int row0 = blockIdx.x * 128;

    int srow[4], scs[4];
#pragma unroll
    for (int i = 0; i < 4; ++i) {
        int ch = wid * 64 + i * 256 + lane;
        int row = ch >> 3, c = ch & 7;
        srow[i] = row;
        scs[i] = (c ^ (row & 7)) * 8;
    }

    f32x4 acc[4][4];
#pragma unroll
    for (int mf = 0; mf < 4; ++mf)
#pragma unroll
        for (int nf = 0; nf < 4; ++nf) { f32x4 z = {0,0,0,0}; acc[mf][nf] = z; }

    for (int kt = 0; kt < 2; ++kt) {
        __syncthreads();
#pragma unroll
        for (int i = 0; i < 4; ++i) {
            int grow = row0 + srow[i]; if (grow >= M) grow = M - 1;
            const float* gx = &x[(size_t)grow * 128 + kt * 64 + scs[i]];
            float4 f0 = *(const float4*)gx;
            float4 f1 = *(const float4*)(gx + 4);
            bf16x8 av = {(bf16)f0.x, (bf16)f0.y, (bf16)f0.z, (bf16)f0.w,
                         (bf16)f1.x, (bf16)f1.y, (bf16)f1.z, (bf16)f1.w};
            *(bf16x8*)((char*)Als + (size_t)(wid * 64 + i * 256 + lane) * 16) = av;
            const bf16* gb = &preWT[(size_t)srow[i] * 128 + kt * 64 + scs[i]];
            bf16* lb = &Bls[(size_t)(wid * 64 + i * 256) * 8];
            __builtin_amdgcn_global_load_lds(
                (const __attribute__((address_space(1))) void*)gb,
                (__attribute__((address_space(3))) void*)lb, 16, 0, 0);
        }
        asm volatile("s_waitcnt vmcnt(0)" ::: "memory");
        __syncthreads();
#pragma unroll
        for (int ks = 0; ks < 2; ++ks) {
            bf16x8 af[4], bfr[4];
#pragma unroll
            for (int mf = 0; mf < 4; ++mf) {
                int r = wm * 64 + mf * 16 + (lane & 15);
                int ch = (ks * 4 + (lane >> 4)) ^ (r & 7);
                af[mf] = *(const bf16x8*)((const char*)Als + r * 128 + ch * 16);
            }
#pragma unroll
            for (int nf = 0; nf < 4; ++nf) {
                int r = wn * 64 + nf * 16 + (lane & 15);
                int ch = (ks * 4 + (lane >> 4)) ^ (r & 7);
                bfr[nf] = *(const bf16x8*)((const char*)Bls + r * 128 + ch * 16);
            }
#pragma unroll
            for (int mf = 0; mf < 4; ++mf)
#pragma unroll
                for (int nf = 0; nf < 4; ++nf)
                    acc[mf][nf] = __builtin_amdgcn_mfma_f32_16x16x32_bf16(
                        af[mf], bfr[nf], acc[mf][nf], 0, 0, 0);
        }
    }
    __syncthreads();

#pragma unroll
    for (int mf = 0; mf < 4; ++mf) {
        int rl = wm * 64 + mf * 16 + (lane >> 4) * 4;
#pragma unroll
        for (int nf = 0; nf < 4; ++nf) {
            int c = wn * 64 + nf * 16 + (lane & 15);
            float bv = pre_b[c];
#pragma unroll
            for (int i = 0; i < 4; ++i) {
                int r = rl + i;
                float v = acc[mf][nf][i] + bv;
                stash_lds((char*)Hbuf, 16384, r, c, v);
                int grow = row0 + r;
                if (grow < M) emb[(size_t)grow * lde + c] = (bf16)v;
            }
        }
    }

#pragma unroll
    for (int mf = 0; mf < 4; ++mf)
#pragma unroll
        for (int nf = 0; nf < 4; ++nf) { f32x4 z = {0,0,0,0}; acc[mf][nf] = z; }

    for (int kt = 0; kt < 2; ++kt) {
        __syncthreads();
#pragma unroll
        for (int i = 0; i < 4; ++i) {
            const bf16* gb = &c0WT[(size_t)srow[i] * 128 + kt * 64 + scs[i]];
            bf16* lb = &Bls[(size_t)(wid * 64 + i * 256) * 8];
            __builtin_amdgcn_global_load_lds(
                (const __attribute__((address_space(1))) void*)gb,
                (__attribute__((address_space(3))) void*)lb, 16, 0, 0);
        }
        asm volatile("s_waitcnt vmcnt(0)" ::: "memory");
        __syncthreads();
#pragma unroll
        for (int ks = 0; ks < 2; ++ks) {
            bf16x8 af[4], bfr[4];
#pragma unroll
            for (int mf = 0; mf < 4; ++mf) {
                int r = wm * 64 + mf * 16 + (lane & 15);
                af[mf] = afrag_lds((const char*)Hbuf, 16384, kt, r, ks, lane);
            }
#pragma unroll
            for (int nf = 0; nf < 4; ++nf) {
                int r = wn * 64 + nf * 16 + (lane & 15);
                int ch = (ks * 4 + (lane >> 4)) ^ (r & 7);
                bfr[nf] = *(const bf16x8*)((const char*)Bls + r * 128 + ch * 16);
            }
#pragma unroll
            for (int mf = 0; mf < 4; ++mf)
#pragma unroll
                for (int nf = 0; nf < 4; ++nf)
                    acc[mf][nf] = __builtin_amdgcn_mfma_f32_16x16x32_bf16(
                        af[mf], bfr[nf], acc[mf][nf], 0, 0, 0);
        }
    }

#pragma unroll
    for (int mf = 0; mf < 4; ++mf) {
        int rbase = row0 + wm * 64 + mf * 16 + (lane >> 4) * 4;
#pragma unroll
        for (int nf = 0; nf < 4; ++nf) {
            int c = wn * 64 + nf * 16 + (lane & 15);
#pragma unroll
            for (int i = 0; i < 4; ++i) {
                int grow = rbase + i;
                if (grow >= M) continue;
                g[(size_t)grow * 128 + c] = (bf16)(acc[mf][nf][i] * dinv[grow]);
            }
        }
    }
}

// ---------------- fused_post: [emb|h4] -> h1 -> h2 -> h3 -> out ----------------
// 64-row tile, LDS 48KB: H1@0 (16K; H3 overlays after stage1), Bls@16K,
// Astage@32K (8K; H2 overlays after stage1 epilogue).
__global__ __launch_bounds__(256) void fused_post(
    const bf16* __restrict__ emb, int lde,
    const bf16* __restrict__ h4,     // n x 128
    const bf16* __restrict__ W1T,    // [128][640]
    const float* __restrict__ b1,
    const bf16* __restrict__ W2T,    // [128][128]
    const float* __restrict__ b2,
    const bf16* __restrict__ W3T,    // [256][128]
    const float* __restrict__ b3,
    const bf16* __restrict__ W4T,    // [128][256]
    const float* __restrict__ b4,
    float* __restrict__ out, int M)
{
    __shared__ char lds[49152];
    bf16* H1  = (bf16*)lds;              // 2kt x 64r x 128B
    bf16* Bls = (bf16*)(lds + 16384);
    bf16* Am  = (bf16*)(lds + 32768);    // stage-0 A staging (8K)
    bf16* H2  = (bf16*)(lds + 32768);    // after stage-1 epilogue
    bf16* H3  = (bf16*)lds;              // overlays H1 (dead after stage 1)

    const int t = threadIdx.x;
    const int lane = t & 63;
    const int wid = t >> 6;
    const int wm = wid >> 1, wn = wid & 1;
    const int row0 = blockIdx.x * 64;

    int srow[4], scs[4];
#pragma unroll
    for (int i = 0; i < 4; ++i) {
        int ch = wid * 64 + i * 256 + lane;
        int row = ch >> 3, c = ch & 7;
        srow[i] = row;
        scs[i] = (c ^ (row & 7)) * 8;
    }

    f32x4 acc[2][4], acc3[2][4];
#pragma unroll
    for (int mf = 0; mf < 2; ++mf)
#pragma unroll
        for (int nf = 0; nf < 4; ++nf) {
            f32x4 z = {0,0,0,0};
            acc[mf][nf] = z;
            acc3[mf][nf] = z;
        }

    // ---- stage 0: h1 = LeakyReLU([emb|h4] @ W1T^T + b1), K=640 ----
    for (int kt = 0; kt < 10; ++kt) {
        const int k0 = kt * 64;
        __syncthreads();
#pragma unroll
        for (int i = 0; i < 2; ++i) {
            int grow = row0 + srow[i]; if (grow >= M) grow = M - 1;
            const bf16* ga = (k0 < 512)
                ? &emb[(size_t)grow * lde + k0 + scs[i]]
                : &h4[(size_t)grow * 128 + (k0 - 512) + scs[i]];
            bf16* la = &Am[(size_t)(wid * 64 + i * 256) * 8];
            __builtin_amdgcn_global_load_lds(
                (const __attribute__((address_space(1))) void*)ga,
                (__attribute__((address_space(3))) void*)la, 16, 0, 0);
        }
#pragma unroll
        for (int i = 0; i < 4; ++i) {
            const bf16* gb = &W1T[(size_t)srow[i] * 640 + k0 + scs[i]];
            bf16* lb = &Bls[(size_t)(wid * 64 + i * 256) * 8];
            __builtin_amdgcn_global_load_lds(
                (const __attribute__((address_space(1))) void*)gb,
                (__attribute__((address_space(3))) void*)lb, 16, 0, 0);
        }
        asm volatile("s_waitcnt vmcnt(0)" ::: "memory");
        __syncthreads();
#pragma unroll
        for (int ks = 0; ks < 2; ++ks) {
            bf16x8 af[2], bfr[4];
#pragma unroll
            for (int mf = 0; mf < 2; ++mf) {
                int r = wm * 32 + mf * 16 + (lane & 15);
                int ch = (ks * 4 + (lane >> 4)) ^ (r & 7);
                af[mf] = *(const bf16x8*)((const char*)Am + r * 128 + ch * 16);
            }
#pragma unroll
            for (int nf = 0; nf < 4; ++nf) {
                int r = wn * 64 + nf * 16 + (lane & 15);
                int ch = (ks * 4 + (lane >> 4)) ^ (r & 7);
                bfr[nf] = *(const bf16x8*)((const char*)Bls + r * 128 + ch * 16);
            }
#pragma unroll
            for (int mf = 0; mf < 2; ++mf)
#pragma unroll
                for (int nf = 0; nf < 4; ++nf)
                    acc[mf][nf] = __builtin_amdgcn_mfma_f32_16x16x32_bf16(
                        af[mf], bfr[nf], acc[mf][nf], 0, 0, 0);
        }
    }
    __syncthreads();
    // epilogue 0 -> H1 (LeakyReLU 0.1)
#pragma unroll
    for (int mf = 0; mf < 2; ++mf) {
        int rl = wm * 32 + mf * 16 + (lane >> 4) * 4;
#pragma unroll
        for (int nf = 0; nf < 4; ++nf) {
            int c = wn * 64 + nf * 16 + (lane & 15);
            float bv = b1[c];
#pragma unroll
            for (int i = 0; i < 4; ++i) {
                float v = acc[mf][nf][i] + bv;
                v = v > 0.f ? v : 0.1f * v;
                stash_lds((char*)H1, 8192, rl + i, c, v);
            }
        }
    }

    // ---- stage 1: h2 = relu(h1 @ W2T^T + b2) ----
#pragma unroll
    for (int mf = 0; mf < 2; ++mf)
#pragma unroll
        for (int nf = 0; nf < 4; ++nf) { f32x4 z = {0,0,0,0}; acc[mf][nf] = z; }
    for (int kt = 0; kt < 2; ++kt) {
        __syncthreads();
#pragma unroll
        for (int i = 0; i < 4; ++i) {
            const bf16* gb = &W2T[(size_t)srow[i] * 128 + kt * 64 + scs[i]];
            bf16* lb = &Bls[(size_t)(wid * 64 + i * 256) * 8];
            __builtin_amdgcn_global_load_lds(
                (const __attribute__((address_space(1))) void*)gb,
                (__attribute__((address_space(3))) void*)lb, 16, 0, 0);
        }
        asm volatile("s_waitcnt vmcnt(0)" ::: "memory");
        __syncthreads();
#pragma unroll
        for (int ks = 0; ks < 2; ++ks) {
            bf16x8 af[2], bfr[4];
#pragma unroll
            for (int mf = 0; mf < 2; ++mf) {
                int r = wm * 32 + mf * 16 + (lane & 15);
                af[mf] = afrag_lds((const char*)H1, 8192, kt, r, ks, lane);
            }
#pragma unroll
            for (int nf = 0; nf < 4; ++nf) {
                int r = wn * 64 + nf * 16 + (lane & 15);
                int ch = (ks * 4 + (lane >> 4)) ^ (r & 7);
                bfr[nf] = *(const bf16x8*)((const char*)Bls + r * 128 + ch * 16);
            }
#pragma unroll
            for (int mf = 0; mf < 2; ++mf)
#pragma unroll
                for (int nf = 0; nf < 4; ++nf)
                    acc[mf][nf] = __builtin_amdgcn_mfma_f32_16x16x32_bf16(
                        af[mf], bfr[nf], acc[mf][nf], 0, 0, 0);
        }
    }
    __syncthreads();   // H1 reads + Am region reads all done
    // epilogue 1 -> H2 (overlays Am)
#pragma unroll
    for (int mf = 0; mf < 2; ++mf) {
        int rl = wm * 32 + mf * 16 + (lane >> 4) * 4;
#pragma unroll
        for (int nf = 0; nf < 4; ++nf) {
            int c = wn * 64 + nf * 16 + (lane & 15);
            float bv = b2[c];
#pragma unroll
            for (int i = 0; i < 4; ++i)
                stash_lds((char*)H2, 8192, rl + i, c, fmaxf(acc[mf][nf][i] + bv, 0.f));
        }
    }

    // ---- halves: h3half = relu(h2 @ W3T^T + b3) ; out += h3half @ W4T^T ----
    for (int hh = 0; hh < 2; ++hh) {
#pragma unroll
        for (int mf = 0; mf < 2; ++mf)
#pragma unroll
            for (int nf = 0; nf < 4; ++nf) { f32x4 z = {0,0,0,0}; acc[mf][nf] = z; }
        for (int kt = 0; kt < 2; ++kt) {
            __syncthreads();
#pragma unroll
            for (int i = 0; i < 4; ++i) {
                const bf16* gb = &W3T[(size_t)(hh * 128 + srow[i]) * 128 + kt * 64 + scs[i]];
                bf16* lb = &Bls[(size_t)(wid * 64 + i * 256) * 8];
                __builtin_amdgcn_global_load_lds(
                    (const __attribute__((address_space(1))) void*)gb,
                    (__attribute__((address_space(3))) void*)lb, 16, 0, 0);
            }
            asm volatile("s_waitcnt vmcnt(0)" ::: "memory");
            __syncthreads();
#pragma unroll
            for (int ks = 0; ks < 2; ++ks) {
                bf16x8 af[2], bfr[4];
#pragma unroll
                for (int mf = 0; mf < 2; ++mf) {
                    int r = wm * 32 + mf * 16 + (lane & 15);
                    af[mf] = afrag_lds((const char*)H2, 8192, kt, r, ks, lane);
                }
#pragma unroll
                for (int nf = 0; nf < 4; ++nf) {
                    int r = wn * 64 + nf * 16 + (lane & 15);
                    int ch = (ks * 4 + (lane >> 4)) ^ (r & 7);
                    bfr[nf] = *(const bf16x8*)((const char*)Bls + r * 128 + ch * 16);
                }
#pragma unroll
                for (int mf = 0; mf < 2; ++mf)
#pragma unroll
                    for (int nf = 0; nf < 4; ++nf)
                        acc[mf][nf] = __builtin_amdgcn_mfma_f32_16x16x32_bf16(
                            af[mf], bfr[nf], acc[mf][nf], 0, 0, 0);
            }
        }
        __syncthreads();   // H3 reads (prev hh) + H1 long dead
        // epilogue 2 -> H3
#pragma unroll
        for (int mf = 0; mf < 2; ++mf) {
            int rl = wm * 32 + mf * 16 + (lane >> 4) * 4;
#pragma unroll
            for (int nf = 0; nf < 4; ++nf) {
                int c = wn * 64 + nf * 16 + (lane & 15);
                float bv = b3[hh * 128 + c];
#pragma unroll
                for (int i = 0; i < 4; ++i)
                    stash_lds((char*)H3, 8192, rl + i, c, fmaxf(acc[mf][nf][i] + bv, 0.f));
            }
        }
        // stage 3: acc3 += H3 @ W4T (k range hh*128 .. +127)
        for (int kt = 0; kt < 2; ++kt) {
            __syncthreads();
#pragma unroll
            for (int i = 0; i < 4; ++i) {
                const bf16* gb = &W4T[(size_t)srow[i] * 256 + hh * 128 + kt * 64 + scs[i]];
                bf16* lb = &Bls[(size_t)(wid * 64 + i * 256) * 8];
                __builtin_amdgcn_global_load_lds(
                    (const __attribute__((address_space(1))) void*)gb,
                    (__attribute__((address_space(3))) void*)lb, 16, 0, 0);
            }
            asm volatile("s_waitcnt vmcnt(0)" ::: "memory");
            __syncthreads();
#pragma unroll
            for (int ks = 0; ks < 2; ++ks) {
                bf16x8 af[2], bfr[4];
#pragma unroll
                for (int mf = 0; mf < 2; ++mf) {
                    int r = wm * 32 + mf * 16 + (lane & 15);
                    af[mf] = afrag_lds((const char*)H3, 8192, kt, r, ks, lane);
                }
#pragma unroll
                for (int nf = 0; nf < 4; ++nf) {
                    int r = wn * 64 + nf * 16 + (lane & 15);
                    int ch = (ks * 4 + (lane >> 4)) ^ (r & 7);
                    bfr[nf] = *(const bf16x8*)((const char*)Bls + r * 128 + ch * 16);
                }
#pragma unroll
                for (int mf = 0; mf < 2; ++mf)
#pragma unroll
                    for (int nf = 0; nf < 4; ++nf)
                        acc3[mf][nf] = __builtin_amdgcn_mfma_f32_16x16x32_bf16(
                            af[mf], bfr[nf], acc3[mf][nf], 0, 0, 0);
            }
        }
    }

    // final epilogue: out = acc3 + b4 (f32)
#pragma unroll
    for (int mf = 0; mf < 2; ++mf) {
        int rbase = row0 + wm * 32 + mf * 16 + (lane >> 4) * 4;
#pragma unroll
        for (int nf = 0; nf < 4; ++nf) {
            int c = wn * 64 + nf * 16 + (lane & 15);
            float bv = b4[c];
#pragma unroll
            for (int i = 0; i < 4; ++i) {
                int grow = rbase + i;
                if (grow < M) out[(size_t)grow * 128 + c] = acc3[mf][nf][i] + bv;
            }
        }
    }
}

// ---------------- fused gather ----------------
__global__ __launch_bounds__(256) void gcn_gather(
    const int* __restrict__ rp, const int* __restrict__ csr,
    const bf16* __restrict__ g, const float* __restrict__ dinv,
    const float* __restrict__ b,
    bf16* __restrict__ out, int ldo, int n)
{
    const int node = (int)(((long long)blockIdx.x * 256 + threadIdx.x) >> 6);
    if (node >= n) return;
    const int lane = threadIdx.x & 63;
    const int grp = lane >> 4;
    const int cc = lane & 15;
    const int start = rp[node];
    const int end = rp[node + 1];

    float acc[8];
#pragma unroll
    for (int j = 0; j < 8; ++j) acc[j] = 0.f;

    int j = start + grp;
    for (; j + 12 < end; j += 16) {
        int s0 = csr[j];
        int s1 = csr[j + 4];
        int s2 = csr[j + 8];
        int s3 = csr[j + 12];
        bf16x8 v0 = *(const bf16x8*)&g[(size_t)s0 * 128 + cc * 8];
        bf16x8 v1 = *(const bf16x8*)&g[(size_t)s1 * 128 + cc * 8];
        bf16x8 v2 = *(const bf16x8*)&g[(size_t)s2 * 128 + cc * 8];
        bf16x8 v3 = *(const bf16x8*)&g[(size_t)s3 * 128 + cc * 8];
#pragma unroll
        for (int jj = 0; jj < 8; ++jj)
            acc[jj] += ((float)v0[jj] + (float)v1[jj]) + ((float)v2[jj] + (float)v3[jj]);
    }
    for (; j < end; j += 4) {
        int s0 = csr[j];
        bf16x8 v0 = *(const bf16x8*)&g[(size_t)s0 * 128 + cc * 8];
#pragma unroll
        for (int jj = 0; jj < 8; ++jj) acc[jj] += (float)v0[jj];
    }
#pragma unroll
    for (int jj = 0; jj < 8; ++jj) {
        acc[jj] += __shfl_xor(acc[jj], 16, 64);
        acc[jj] += __shfl_xor(acc[jj], 32, 64);
    }
    if (grp == 0) {
        bf16x8 sv = *(const bf16x8*)&g[(size_t)node * 128 + cc * 8];
        float s = dinv[node];
        bf16x8 o;
#pragma unroll
        for (int jj = 0; jj < 8; ++jj) {
            float v = fmaf(s, acc[jj] + (float)sv[jj], b[cc * 8 + jj]);
            o[jj] = (bf16)fmaxf(v, 0.f);
        }
        *(bf16x8*)&out[(size_t)node * ldo + cc * 8] = o;
    }
}

// ---------------- launcher ----------------
extern "C" void kernel_launch(void* const* d_in, const int* in_sizes, int n_in,
                              void* d_out, int out_size, void* d_ws, size_t ws_size,
                              hipStream_t stream) {
    const float* x      = (const float*)d_in[0];
    const int*   ei     = (const int*)d_in[1];
    const float* pre_w  = (const float*)d_in[2];
    const float* pre_b  = (const float*)d_in[3];
    const float* conv_w[4] = {(const float*)d_in[4], (const float*)d_in[6],
                              (const float*)d_in[8], (const float*)d_in[10]};
    const float* conv_b[4] = {(const float*)d_in[5], (const float*)d_in[7],
                              (const float*)d_in[9], (const float*)d_in[11]};
    const float* post_w1 = (const float*)d_in[12];
    const float* post_b1 = (const float*)d_in[13];
    const float* post_w2 = (const float*)d_in[14];
    const float* post_b2 = (const float*)d_in[15];
    const float* post_w3 = (const float*)d_in[16];
    const float* post_b3 = (const float*)d_in[17];
    const float* post_w4 = (const float*)d_in[18];
    const float* post_b4 = (const float*)d_in[19];

    const int n = in_sizes[0] / 128;        // 100000
    const int E = in_sizes[1] / 2;          // 1600000
    const int NBKT = (n + 511) >> BSHIFT;   // 196 buckets
    const int NBLK = (E + PCHUNK - 1) / PCHUNK;  // 391 partition blocks

    // ws layout (bytes)
    size_t off = 0;
    bf16* emb  = (bf16*)((char*)d_ws + off); off += (size_t)n * 512 * 2;
    bf16* g    = (bf16*)((char*)d_ws + off); off += (size_t)n * 128 * 2;
    bf16* h4   = (bf16*)((char*)d_ws + off); off += (size_t)n * 128 * 2;
    float* dinv = (float*)((char*)d_ws + off); off += (size_t)n * 4;
    int*   rp   = (int*)((char*)d_ws + off); off += (size_t)(n + 4) * 4;
    int*   csr  = (int*)((char*)d_ws + off); off += (size_t)E * 4;
    int2*  sorted = (int2*)((char*)d_ws + off); off += (size_t)E * 8;
    bf16*  wt   = (bf16*)((char*)d_ws + off); off += (size_t)344064 * 2;
    int*   bcountT = (int*)((char*)d_ws + off); off += (size_t)NBKT * NBLK * 4;
    int*   btot    = (int*)((char*)d_ws + off); off += (size_t)NBKT * 4;
    int*   bbase   = (int*)((char*)d_ws + off); off += (size_t)(NBKT + 1) * 4;
    if (ws_size < off) return;  // diagnostic early-out

    // weight-pool offsets (elements)
    bf16* pre_wt  = wt;            // [128][128]
    bf16* c_wt0   = wt + 16384;
    bf16* c_wt1   = wt + 32768;
    bf16* c_wt2   = wt + 65536;
    bf16* c_wt3   = wt + 114688;
    bf16* p1_wt   = wt + 180224;   // [128][640]
    bf16* p2_wt   = wt + 262144;
    bf16* p3_wt   = wt + 278528;   // [256][128]
    bf16* p4_wt   = wt + 311296;   // [128][256]
    bf16* c_wt[4] = {c_wt0, c_wt1, c_wt2, c_wt3};

    // ---- CSR build: bucket partition (no global atomics) ----
    part_count<<<NBLK, 256, 0, stream>>>(ei, bcountT, NBKT, NBLK, E);
    part_scanb<<<NBKT, 256, 0, stream>>>(bcountT, btot, NBLK);
    part_scant<<<1, 256, 0, stream>>>(btot, bbase, NBKT, E);
    part_scatter<<<NBLK, 256, 0, stream>>>(ei, bcountT, bbase, sorted, NBKT, NBLK, E);
    bucket_csr<<<NBKT, 512, 0, stream>>>(sorted, bbase, rp, dinv, csr, n, E);

    // ---- all weight transposes in one launch ----
    TAll ta;
    ta.src[0] = pre_w;   ta.K[0] = 128; ta.N[0] = 128;
    ta.src[1] = conv_w[0]; ta.K[1] = 128; ta.N[1] = 128;
    ta.src[2] = conv_w[1]; ta.K[2] = 256; ta.N[2] = 128;
    ta.src[3] = conv_w[2]; ta.K[3] = 384; ta.N[3] = 128;
    ta.src[4] = conv_w[3]; ta.K[4] = 512; ta.N[4] = 128;
    ta.src[5] = post_w1;  ta.K[5] = 640; ta.N[5] = 128;
    ta.src[6] = post_w2;  ta.K[6] = 128; ta.N[6] = 128;
    ta.src[7] = post_w3;  ta.K[7] = 128; ta.N[7] = 256;
    ta.src[8] = post_w4;  ta.K[8] = 256; ta.N[8] = 128;
    ta.cum[0] = 0;
    for (int s = 0; s < 9; ++s) ta.cum[s + 1] = ta.cum[s] + ta.K[s] * ta.N[s];
    const int wtot = ta.cum[9];   // 344064
    transpose_all<<<(wtot + 255) / 256, 256, 0, stream>>>(ta, wt, wtot);

    const int gx = (n + 127) / 128;   // 782
    const int gx2 = (n + 63) / 64;    // 1563
    auto gemm = [&](const bf16* A1, int lda1, int K1, const bf16* A2, int lda2,
                    const bf16* WT, const float* bias, const float* rs,
                    void* C, int ldc, int Ktot, int N, int act, int outf32) {
        dim3 grid(gx, N / 128);
        gemm_bf16<<<grid, 256, 0, stream>>>(A1, lda1, K1, A2, lda2, WT, bias, rs,
                                            C, ldc, n, Ktot, act, outf32);
    };

    const int ggrid = (int)(((long long)n * 64 + 255) / 256);
    for (int l = 0; l < 4; ++l) {
        if (l == 0) {
            fused_pre<<<gx, 256, 0, stream>>>(x, pre_wt, pre_b, c_wt0, dinv,
                                              emb, 512, g, n);
        } else {
            int K = 128 * (l + 1);
            gemm(emb, 512, K, emb, 512, c_wt[l], nullptr, dinv, g, 128, K, 128, 0, 0);
        }
        bf16* out = (l < 3) ? (emb + (size_t)128 * (l + 1)) : h4;
        int ldo = (l < 3) ? 512 : 128;
        gcn_gather<<<ggrid, 256, 0, stream>>>(rp, csr, g, dinv, conv_b[l], out, ldo, n);
    }

    // post_mp: single fused kernel (h1/h2/h3 never touch HBM)
    fused_post<<<gx2, 256, 0, stream>>>(emb, 512, h4,
                                        p1_wt, post_b1, p2_wt, post_b2,
                                        p3_wt, post_b3, p4_wt, post_b4,
                                        (float*)d_out, n);
}